// Round 9
// baseline (414.044 us; speedup 1.0000x reference)
//
#include <hip/hip_runtime.h>
#include <cstdint>

typedef unsigned short u16;
typedef __attribute__((ext_vector_type(8))) short short8;
typedef __attribute__((ext_vector_type(8))) __bf16 bf16x8;
typedef __attribute__((ext_vector_type(4))) float f32x4;

#define DEV __device__ __forceinline__

DEV u16 f2bf(float f){
  uint32_t u = __float_as_uint(f);
  u += 0x7fffu + ((u >> 16) & 1u);
  return (u16)(u >> 16);
}
DEV float bf2f(u16 h){ return __uint_as_float(((uint32_t)h) << 16); }
DEV u16 f2h(float f){ return __builtin_bit_cast(u16, (_Float16)f); }
DEV float h2f(u16 h){ return (float)__builtin_bit_cast(_Float16, h); }

DEV f32x4 mfma16(short8 a, short8 b, f32x4 c){
  return __builtin_amdgcn_mfma_f32_16x16x32_bf16(
      __builtin_bit_cast(bf16x8, a), __builtin_bit_cast(bf16x8, b), c, 0, 0, 0);
}

#define NN 10000
#define EE 160000
#define MPN 10112   /* 79*128  */
#define MPE 160128  /* 1251*128 */

// ---------------- CSR build: count + scan in ONE single-block kernel ----------------
__global__ __launch_bounds__(1024) void csr1_k(const int* __restrict__ dst,
                                               int* __restrict__ offs,
                                               int* __restrict__ cursor){
  __shared__ int hist[NN];
  __shared__ int psum[1024];
  int tid = threadIdx.x;
  for(int i = tid; i < NN; i += 1024) hist[i] = 0;
  __syncthreads();
  for(int i = tid; i < EE; i += 1024) atomicAdd(&hist[dst[i]], 1);
  __syncthreads();
  // per-thread chunk of 10: local exclusive scan
  int base = tid * 10;
  int s = 0;
  #pragma unroll
  for(int j = 0; j < 10; ++j){
    int idx = base + j;
    if(idx < NN){ int t = hist[idx]; hist[idx] = s; s += t; }
  }
  psum[tid] = s;
  __syncthreads();
  for(int d = 1; d < 1024; d <<= 1){
    int t = (tid >= d) ? psum[tid - d] : 0;
    __syncthreads();
    psum[tid] += t;
    __syncthreads();
  }
  int add = (tid > 0) ? psum[tid - 1] : 0;
  #pragma unroll
  for(int j = 0; j < 10; ++j){
    int idx = base + j;
    if(idx < NN){ int v = hist[idx] + add; offs[idx] = v; cursor[idx] = v; }
  }
  if(tid == 0) offs[NN] = EE;
}

__global__ void scatter_k(const int* __restrict__ dst, int* __restrict__ cursor,
                          int* __restrict__ eids){
  int i = blockIdx.x * 256 + threadIdx.x;
  if(i < EE){ int p = atomicAdd(&cursor[dst[i]], 1); eids[p] = i; }
}

// deterministic rank: slot(e) = offs[dst] + #{e' in bucket : e' < e}
__global__ void rank_k(const int* __restrict__ dst, const int* __restrict__ src,
                       const int* __restrict__ offs, const int* __restrict__ eids,
                       int* __restrict__ eidp, int* __restrict__ srcp){
  int e = blockIdx.x * 256 + threadIdx.x;
  if(e >= MPE) return;
  if(e >= EE){ eidp[e] = e; return; }      // pad slots -> zero rows of eabf
  int n = dst[e];
  int p0 = offs[n], p1 = offs[n + 1];
  int rk = 0;
  for(int p = p0; p < p1; ++p) rk += (eids[p] < e) ? 1 : 0;
  int slot = p0 + rk;
  eidp[slot] = e;
  srcp[slot] = src[e];
}

// ---------------- weight / input prep (single fused kernel) ----------------
struct WPack {
  const float* Wq[3]; const float* Wk[3]; const float* Wv[3];
  const float* Ws[3]; const float* We[3];
  const float* bq[3]; const float* bk[3]; const float* bv[3]; const float* bs[3];
};

#define PG0 5056                 /* xbf   : MPN*128/256 */
#define PG1 (PG0 + 20016)        /* eabf  : MPE*32/256  */
#define PG2 (PG1 + 3840)         /* Wcat/Wet : 3*1280   */
#define PG3 (PG2 + 1536)         /* WqBF/WeBF: 3*512    */
#define PG4 (PG3 + 15)           /* biasc */
#define PG5 (PG4 + 256)          /* encoders */

// Wcat rows per layer: [0,256) Wq^T | [256,512) Ws^T | [512,768) qWe (GEMM EPI5)
//                      | [768,1024) Wk^T | [1024,1280) Wv^T
__global__ __launch_bounds__(256) void prep_all_k(
    const float* __restrict__ x, const float* __restrict__ eattr, WPack P,
    const float* __restrict__ Wne, const float* __restrict__ Wee,
    u16* __restrict__ xbf, u16* __restrict__ eabf,
    u16* __restrict__ Wcat, u16* __restrict__ Wet,
    u16* __restrict__ WqBF, u16* __restrict__ WeBF,
    float* __restrict__ biasc, u16* __restrict__ Wnet, u16* __restrict__ Weet)
{
  int b = blockIdx.x, tid = threadIdx.x;
  if(b < PG0){
    int i = b * 256 + tid;
    xbf[i] = (i < NN * 128) ? f2bf(x[i]) : (u16)0;
  } else if(b < PG1){
    int i = (b - PG0) * 256 + tid;
    eabf[i] = (i < EE * 32) ? f2bf(eattr[i]) : (u16)0;
  } else if(b < PG2){
    int b2 = b - PG1; int l = b2 / 1280, r = b2 % 1280; int k = tid;
    float v;
    if(r < 256)       v = P.Wq[l][k * 256 + r];
    else if(r < 512)  v = P.Ws[l][k * 256 + (r - 256)];
    else if(r < 768){ Wet[((size_t)l * 256 + (r - 512)) * 256 + k] =
                        f2bf(P.We[l][k * 256 + (r - 512)]); return; }
    else if(r < 1024) v = P.Wk[l][k * 256 + (r - 768)];
    else              v = P.Wv[l][k * 256 + (r - 1024)];
    Wcat[((size_t)l * 1280 + r) * 256 + k] = f2bf(v);
  } else if(b < PG3){
    int b3 = b - PG2; int l = b3 >> 9, rr = b3 & 511; int t = tid;
    if(rr < 256) WqBF[((size_t)l * 256 + rr) * 256 + t] = f2bf(P.Wq[l][rr * 256 + t]);
    else         WeBF[((size_t)l * 256 + (rr - 256)) * 256 + t] = f2bf(P.We[l][(rr - 256) * 256 + t]);
  } else if(b < PG4){
    int b4 = b - PG3; int l = b4 / 5, seg = b4 % 5; int t = tid;
    float v;
    if(seg == 0)      v = P.bq[l][t];
    else if(seg == 1) v = P.bs[l][t];
    else if(seg == 2){
      const float* we = P.We[l] + (size_t)t * 256; const float* bq = P.bq[l];
      float s = 0.f;
      for(int c = 0; c < 256; ++c) s += bq[c] * we[c];
      v = s;
    }
    else if(seg == 3) v = P.bk[l][t];
    else              v = P.bv[l][t];
    biasc[(size_t)l * 1280 + seg * 256 + t] = v;
  } else {
    int n = b - PG4;
    if(tid < 128) Wnet[n * 128 + tid] = f2bf(Wne[(size_t)tid * 256 + n]);
    if(tid < 32)  Weet[n * 32 + tid]  = f2bf(Wee[(size_t)tid * 256 + n]);
  }
}

// ---------------- MFMA GEMM body:  C[M,N] = A[M,K](bf16) @ Bt[N,K]^T(bf16) ----------------
// AG: gather A rows through rowmap.
// EPI 0: +bias; sec(by/2): 0 q->Out(ld512) | 1 skip->skipOut fp16(ld256)
//        | 2 qWe->Out(+256) | 3 k->kvout | 4 v->kvout(+256)
// EPI 1: +bias, relu -> bf16 (Out, ld Nld)
// EPI 3: acc + accv(fp16) + skip(fp16), relu -> bf16
// EPI 4: acc + accv(fp16) + skip(fp16) -> fp32
// EPI 5: plain -> bf16 (weight-prep GEMM; batched over bz)
template<int BK, int EPI, int AG>
DEV void gemm_body(short8* smem8,
    const u16* __restrict__ A, const u16* __restrict__ Bt,
    const float* __restrict__ bias, void* Out,
    const u16* __restrict__ accvH, const u16* __restrict__ skipH,
    const int* __restrict__ rowmap, u16* __restrict__ kvout,
    u16* __restrict__ skipOut,
    int bx, int by, int bz,
    int Mreal, int Nld, int K, size_t sA, size_t sB, size_t sOb)
{
  constexpr int CPR = BK / 8;           // 16B chunks per LDS row
  constexpr int SW  = (BK == 64) ? 7 : 3;
  u16* Al = (u16*)smem8;
  u16* Bl = Al + 128 * BK;
  A  += (size_t)bz * sA;
  Bt += (size_t)bz * sB;
  Out = (void*)((char*)Out + (size_t)bz * sOb);
  int tid = threadIdx.x, lane = tid & 63;
  int rowBase = bx * 128, colBase = by * 128;
  int wave = tid >> 6, wm = wave >> 1, wn = wave & 1;
  int lr = lane & 15, lk = lane >> 4;
  f32x4 acc[4][4] = {};
  int nkt = K / BK;
  for(int kt = 0; kt < nkt; ++kt){
    __syncthreads();
    for(int ci = tid; ci < 128 * CPR; ci += 256){
      int r = ci / CPR, cb = ci % CPR;
      int ar = AG ? rowmap[rowBase + r] : (rowBase + r);
      int d = (r * CPR + (cb ^ (r & SW))) * 8;     // swizzled dest (u16 units)
      *(short8*)&Al[d] = *(const short8*)&A [(size_t)ar * K + kt * BK + cb * 8];
      *(short8*)&Bl[d] = *(const short8*)&Bt[(size_t)(colBase + r) * K + kt * BK + cb * 8];
    }
    __syncthreads();
    #pragma unroll
    for(int kk = 0; kk < BK / 32; ++kk){
      short8 af[4], bfr[4];
      #pragma unroll
      for(int m = 0; m < 4; ++m){
        int r = wm * 64 + m * 16 + lr;
        int byt = r * (BK * 2) + kk * 64 + lk * 16; byt ^= (r & SW) << 4;
        af[m] = *(const short8*)((const char*)Al + byt);
      }
      #pragma unroll
      for(int n = 0; n < 4; ++n){
        int r = wn * 64 + n * 16 + lr;
        int byt = r * (BK * 2) + kk * 64 + lk * 16; byt ^= (r & SW) << 4;
        bfr[n] = *(const short8*)((const char*)Bl + byt);
      }
      #pragma unroll
      for(int m = 0; m < 4; ++m)
        #pragma unroll
        for(int n = 0; n < 4; ++n)
          acc[m][n] = mfma16(af[m], bfr[n], acc[m][n]);
    }
  }

  // ---------- epilogue: LDS-staged, vectorized 16B stores ----------
  __syncthreads();                       // all ds_reads done before LDS reuse
  if constexpr(EPI == 4){
    float* fs = (float*)smem8;           // [64][128] fp32, two passes
    #pragma unroll
    for(int h = 0; h < 2; ++h){
      if(wm == h){
        #pragma unroll
        for(int m = 0; m < 4; ++m)
          #pragma unroll
          for(int n = 0; n < 4; ++n){
            int cc = wn * 64 + n * 16 + lr;
            int c = colBase + cc;
            #pragma unroll
            for(int j = 0; j < 4; ++j){
              int r2 = m * 16 + lk * 4 + j;
              int r = rowBase + h * 64 + r2;
              fs[r2 * 128 + cc] = acc[m][n][j]
                + h2f(accvH[(size_t)r * 256 + c]) + h2f(skipH[(size_t)r * 256 + c]);
            }
          }
      }
      __syncthreads();
      for(int ch = tid; ch < 2048; ch += 256){
        int rr = ch >> 5, cc = (ch & 31) << 2;
        int r = rowBase + h * 64 + rr;
        if(r < Mreal)
          *(float4*)&((float*)Out)[(size_t)r * Nld + colBase + cc] = *(float4*)&fs[rr * 128 + cc];
      }
      __syncthreads();
    }
  } else if constexpr(EPI == 0){
    int sec = by >> 1;                   // 0 q | 1 skip | 2 qWe | 3 k | 4 v
    u16* us = (u16*)smem8;               // [128][128] u16 (bf16 or fp16)
    #pragma unroll
    for(int m = 0; m < 4; ++m)
      #pragma unroll
      for(int n = 0; n < 4; ++n){
        int cc = wn * 64 + n * 16 + lr;
        #pragma unroll
        for(int j = 0; j < 4; ++j){
          int rr = wm * 64 + m * 16 + lk * 4 + j;
          float v = acc[m][n][j] + bias[colBase + cc];
          us[rr * 128 + cc] = (sec == 1) ? f2h(v) : f2bf(v);
        }
      }
    __syncthreads();
    u16* dstp; int cofs, ldd;
    if(sec == 0){ dstp = (u16*)Out; cofs = colBase; ldd = 512; }
    else if(sec == 1){ dstp = skipOut; cofs = colBase - 256; ldd = 256; }
    else if(sec == 2){ dstp = (u16*)Out; cofs = colBase - 256; ldd = 512; }
    else { dstp = kvout; cofs = colBase - 768; ldd = 512; }
    for(int ch = tid; ch < 2048; ch += 256){
      int rr = ch >> 4, cc = (ch & 15) << 3;
      int r = rowBase + rr;
      if(r < Mreal)
        *(short8*)&dstp[(size_t)r * ldd + cofs + cc] = *(short8*)&us[rr * 128 + cc];
    }
  } else {
    // bf16 single-pass: EPI 1 (bias+relu), 3 (accv+skip+relu), 5 (plain)
    u16* us = (u16*)smem8;               // [128][128] bf16
    #pragma unroll
    for(int m = 0; m < 4; ++m)
      #pragma unroll
      for(int n = 0; n < 4; ++n){
        int cc = wn * 64 + n * 16 + lr;
        int c = colBase + cc;
        #pragma unroll
        for(int j = 0; j < 4; ++j){
          int rr = wm * 64 + m * 16 + lk * 4 + j;
          float v = acc[m][n][j];
          if constexpr(EPI == 1){ v += bias[c]; v = fmaxf(v, 0.f); }
          else if constexpr(EPI == 3){
            int r = rowBase + rr;
            v += h2f(accvH[(size_t)r * 256 + c]) + h2f(skipH[(size_t)r * 256 + c]);
            v = fmaxf(v, 0.f);
          }
          us[rr * 128 + cc] = f2bf(v);
        }
      }
    __syncthreads();
    for(int ch = tid; ch < 2048; ch += 256){
      int rr = ch >> 4, cc = (ch & 15) << 3;
      int r = rowBase + rr;
      if(r < Mreal)
        *(short8*)&((u16*)Out)[(size_t)r * Nld + colBase + cc] = *(short8*)&us[rr * 128 + cc];
    }
  }
}

// ---------------- GEMM kernel wrappers ----------------
__global__ __launch_bounds__(256) void slab_k(
    const u16* __restrict__ A, const u16* __restrict__ Bt,
    const float* __restrict__ bias, u16* __restrict__ qq,
    u16* __restrict__ kvout, u16* __restrict__ skipOut){
  __shared__ short8 smem[2048];
  gemm_body<64,0,0>(smem, A, Bt, bias, qq, nullptr, nullptr, nullptr, kvout, skipOut,
                    blockIdx.x, blockIdx.y, 0, NN, 512, 256, 0, 0, 0);
}

__global__ __launch_bounds__(256) void out3_k(
    const u16* __restrict__ A, const u16* __restrict__ Bt, u16* __restrict__ Out,
    const u16* __restrict__ accvH, const u16* __restrict__ skipH){
  __shared__ short8 smem[2048];
  gemm_body<64,3,0>(smem, A, Bt, nullptr, Out, accvH, skipH, nullptr, nullptr, nullptr,
                    blockIdx.x, blockIdx.y, 0, NN, 256, 256, 0, 0, 0);
}

__global__ __launch_bounds__(256) void out4_k(
    const u16* __restrict__ A, const u16* __restrict__ Bt, float* __restrict__ Out,
    const u16* __restrict__ accvH, const u16* __restrict__ skipH){
  __shared__ short8 smem[2048];
  gemm_body<64,4,0>(smem, A, Bt, nullptr, Out, accvH, skipH, nullptr, nullptr, nullptr,
                    blockIdx.x, blockIdx.y, 0, NN, 256, 256, 0, 0, 0);
}

// node-enc (158 blocks) + edge-enc (2502) + weight GEMMs (12) in one launch
__global__ __launch_bounds__(256) void enc_all_k(
    const u16* __restrict__ xbf, const u16* __restrict__ Wnet,
    const float* __restrict__ bne, u16* __restrict__ hbf,
    const u16* __restrict__ eabf, const u16* __restrict__ Weet,
    const float* __restrict__ bee, u16* __restrict__ efp, const int* __restrict__ eidp,
    const u16* __restrict__ WeBF, const u16* __restrict__ WqBF, u16* __restrict__ WcatQ){
  __shared__ short8 smem[2048];
  int b = blockIdx.x;
  if(b < 158){
    gemm_body<64,1,0>(smem, xbf, Wnet, bne, hbf, nullptr, nullptr, nullptr, nullptr, nullptr,
                      b >> 1, b & 1, 0, NN, 256, 128, 0, 0, 0);
  } else if(b < 2660){
    int bb = b - 158;
    gemm_body<32,1,1>(smem, eabf, Weet, bee, efp, nullptr, nullptr, eidp, nullptr, nullptr,
                      bb >> 1, bb & 1, 0, EE, 256, 32, 0, 0, 0);
  } else {
    int bb = b - 2660;   // 12 blocks: bx = bb&1, by = (bb>>1)&1, bz = bb>>2
    gemm_body<64,5,0>(smem, WeBF, WqBF, nullptr, WcatQ, nullptr, nullptr, nullptr, nullptr, nullptr,
                      bb & 1, (bb >> 1) & 1, bb >> 2, 256, 256, 256,
                      (size_t)256 * 256, (size_t)256 * 256, (size_t)1280 * 256 * 2);
  }
}

// ---------------- fused per-node attention pass ----------------
// qq row (ld 512 bf16): q[0:256) qWe[256:512)
// kvbf row (ld 512 bf16): k[0:256) v[256:512)
// efp row (ld 256 bf16): edge features in CSR slot order
// ONE node per WAVE; per 64-edge window, group eg owns edges [t*64+eg*16,+16):
// each group loads its OWN srcp slice and broadcasts GROUP-LOCALLY (gb+j) —
// cross-group __shfl under divergent exec reads inactive lanes (returns 0) and
// was the R6/R8 0.481 bug. accv/ agg written fp16/bf16.
__global__ __launch_bounds__(256) void node_pass_k(
    const u16* __restrict__ qq, const u16* __restrict__ efp,
    const u16* __restrict__ kvbf,
    const int* __restrict__ srcp, const int* __restrict__ offs,
    u16* __restrict__ accvH, u16* __restrict__ aggef)
{
  int wave = threadIdx.x >> 6, lane = threadIdx.x & 63;
  int n = blockIdx.x * 4 + wave;
  if(n >= NN) return;
  int li = lane & 15, eg = lane >> 4, gb = lane & 48;
  const u16* qrow = qq + (size_t)n * 512 + li * 16;
  short8 qh0 = *(const short8*)(qrow),       qh1 = *(const short8*)(qrow + 8);
  short8 eh0 = *(const short8*)(qrow + 256), eh1 = *(const short8*)(qrow + 264);
  float q[16], e[16];
  #pragma unroll
  for(int d = 0; d < 8; ++d){
    q[d] = bf2f((u16)qh0[d]); q[8 + d] = bf2f((u16)qh1[d]);
    e[d] = bf2f((u16)eh0[d]); e[8 + d] = bf2f((u16)eh1[d]);
  }
  float av[16], ag[16];
  #pragma unroll
  for(int d = 0; d < 16; ++d){ av[d] = 0.f; ag[d] = 0.f; }
  float den = 0.f;
  int p0 = offs[n], deg = offs[n + 1] - p0;
  int nwin = (deg + 63) >> 6;                       // uniform across the wave
  for(int t = 0; t < nwin; ++t){
    int gstart = t * 64 + eg * 16;                  // this group's sub-window
    int rem = deg - gstart;
    int scnt = rem < 16 ? (rem < 0 ? 0 : rem) : 16;
    int ssrc = (li < scnt) ? srcp[p0 + gstart + li] : 0;  // group-local 16-read
    int jj = 0;
    for(; jj + 1 < scnt; jj += 2){
      int s1 = __shfl(ssrc, gb + jj);               // group-local broadcast
      int s2 = __shfl(ssrc, gb + jj + 1);
      size_t pp = (size_t)(p0 + gstart + jj);
      const u16* kv1 = kvbf + ((size_t)s1 << 9) + li * 16;
      const u16* kv2 = kvbf + ((size_t)s2 << 9) + li * 16;
      const u16* e1 = efp + (pp << 8) + li * 16;
      const u16* e2 = efp + ((pp + 1) << 8) + li * 16;
      short8 kA1 = *(const short8*)(kv1),       kB1 = *(const short8*)(kv1 + 8);
      short8 vA1 = *(const short8*)(kv1 + 256), vB1 = *(const short8*)(kv1 + 264);
      short8 fA1 = *(const short8*)(e1),        fB1 = *(const short8*)(e1 + 8);
      short8 kA2 = *(const short8*)(kv2),       kB2 = *(const short8*)(kv2 + 8);
      short8 vA2 = *(const short8*)(kv2 + 256), vB2 = *(const short8*)(kv2 + 264);
      short8 fA2 = *(const short8*)(e2),        fB2 = *(const short8*)(e2 + 8);
      float sc1 = 0.f, sc2 = 0.f;
      #pragma unroll
      for(int d = 0; d < 8; ++d){
        sc1 += q[d]   * bf2f((u16)kA1[d]) + e[d]   * bf2f((u16)fA1[d]);
        sc1 += q[8+d] * bf2f((u16)kB1[d]) + e[8+d] * bf2f((u16)fB1[d]);
        sc2 += q[d]   * bf2f((u16)kA2[d]) + e[d]   * bf2f((u16)fA2[d]);
        sc2 += q[8+d] * bf2f((u16)kB2[d]) + e[8+d] * bf2f((u16)fB2[d]);
      }
      sc1 += __shfl_xor(sc1, 1); sc2 += __shfl_xor(sc2, 1);
      sc1 += __shfl_xor(sc1, 2); sc2 += __shfl_xor(sc2, 2);
      sc1 += __shfl_xor(sc1, 4); sc2 += __shfl_xor(sc2, 4);
      sc1 += __shfl_xor(sc1, 8); sc2 += __shfl_xor(sc2, 8);
      float w1 = __expf(sc1 * 0.0625f);
      float w2 = __expf(sc2 * 0.0625f);
      den += w1 + w2;
      #pragma unroll
      for(int d = 0; d < 8; ++d){
        av[d]   += w1 * bf2f((u16)vA1[d]) + w2 * bf2f((u16)vA2[d]);
        av[8+d] += w1 * bf2f((u16)vB1[d]) + w2 * bf2f((u16)vB2[d]);
        ag[d]   += w1 * bf2f((u16)fA1[d]) + w2 * bf2f((u16)fA2[d]);
        ag[8+d] += w1 * bf2f((u16)fB1[d]) + w2 * bf2f((u16)fB2[d]);
      }
    }
    if(jj < scnt){
      int s = __shfl(ssrc, gb + jj);                // group-local broadcast
      size_t pp = (size_t)(p0 + gstart + jj);
      const u16* kvp = kvbf + ((size_t)s << 9) + li * 16;
      const u16* ep = efp + (pp << 8) + li * 16;
      short8 kA = *(const short8*)(kvp),       kB = *(const short8*)(kvp + 8);
      short8 vA = *(const short8*)(kvp + 256), vB = *(const short8*)(kvp + 264);
      short8 fA = *(const short8*)(ep),        fB = *(const short8*)(ep + 8);
      float part = 0.f;
      #pragma unroll
      for(int d = 0; d < 8; ++d){
        part += q[d]   * bf2f((u16)kA[d]) + e[d]   * bf2f((u16)fA[d]);
        part += q[8+d] * bf2f((u16)kB[d]) + e[8+d] * bf2f((u16)fB[d]);
      }
      part += __shfl_xor(part, 1);
      part += __shfl_xor(part, 2);
      part += __shfl_xor(part, 4);
      part += __shfl_xor(part, 8);
      float wgt = __expf(part * 0.0625f);
      den += wgt;
      #pragma unroll
      for(int d = 0; d < 8; ++d){
        av[d]   += wgt * bf2f((u16)vA[d]);
        av[8+d] += wgt * bf2f((u16)vB[d]);
        ag[d]   += wgt * bf2f((u16)fA[d]);
        ag[8+d] += wgt * bf2f((u16)fB[d]);
      }
    }
  }
  // combine the 4 edge-groups (convergent — all 64 lanes active here)
  #pragma unroll
  for(int d = 0; d < 16; ++d){
    av[d] += __shfl_xor(av[d], 16); av[d] += __shfl_xor(av[d], 32);
    ag[d] += __shfl_xor(ag[d], 16); ag[d] += __shfl_xor(ag[d], 32);
  }
  den += __shfl_xor(den, 16); den += __shfl_xor(den, 32);
  float rden = 1.f / fmaxf(den, 1e-16f);          // pre-divide (linear in We)
  if(eg == 0){
    u16* ao = accvH + (size_t)n * 256 + li * 16;
    #pragma unroll
    for(int t = 0; t < 2; ++t){
      short8 o;
      #pragma unroll
      for(int d = 0; d < 8; ++d) o[d] = (short)f2h(av[t*8+d] * rden);
      *(short8*)(ao + t * 8) = o;
    }
  } else if(eg == 1){
    u16* go = aggef + (size_t)n * 256 + li * 16;
    #pragma unroll
    for(int t = 0; t < 2; ++t){
      short8 o;
      #pragma unroll
      for(int d = 0; d < 8; ++d) o[d] = (short)f2bf(ag[t*8+d] * rden);
      *(short8*)(go + t * 8) = o;
    }
  }
}

// ---------------- launch ----------------
extern "C" void kernel_launch(void* const* d_in, const int* in_sizes, int n_in,
                              void* d_out, int out_size, void* d_ws, size_t ws_size,
                              hipStream_t stream){
  const float* x     = (const float*)d_in[0];
  const float* eattr = (const float*)d_in[1];
  const int*   src   = (const int*)d_in[2];
  const int*   dst   = (const int*)d_in[3];
  const float* Wee   = (const float*)d_in[4];
  const float* bee   = (const float*)d_in[5];
  const float* Wne   = (const float*)d_in[6];
  const float* bne   = (const float*)d_in[7];
  WPack P;
  for(int l = 0; l < 3; ++l){
    const int b = 8 + l * 9;
    P.Wq[l] = (const float*)d_in[b + 0]; P.bq[l] = (const float*)d_in[b + 1];
    P.Wk[l] = (const float*)d_in[b + 2]; P.bk[l] = (const float*)d_in[b + 3];
    P.Wv[l] = (const float*)d_in[b + 4]; P.bv[l] = (const float*)d_in[b + 5];
    P.We[l] = (const float*)d_in[b + 6];
    P.Ws[l] = (const float*)d_in[b + 7]; P.bs[l] = (const float*)d_in[b + 8];
  }

  char* w = (char*)d_ws; size_t off = 0;
  auto alloc = [&](size_t bytes)->char*{
    char* p = w + off; off = (off + bytes + 255) & ~(size_t)255; return p;
  };
  u16*   Wcat  = (u16*)  alloc((size_t)3 * 1280 * 256 * 2);
  u16*   Wet   = (u16*)  alloc((size_t)3 * 256 * 256 * 2);
  u16*   WqBF  = (u16*)  alloc((size_t)3 * 256 * 256 * 2);
  u16*   WeBF  = (u16*)  alloc((size_t)3 * 256 * 256 * 2);
  float* biasc = (float*)alloc((size_t)3 * 1280 * 4);
  u16*   Wnet  = (u16*)  alloc((size_t)256 * 128 * 2);
  u16*   Weet  = (u16*)  alloc((size_t)256 * 32 * 2);
  u16*   xbf   = (u16*)  alloc((size_t)MPN * 128 * 2);
  u16*   eabf  = (u16*)  alloc((size_t)MPE * 32 * 2);
  u16*   hbf   = (u16*)  alloc((size_t)MPN * 256 * 2);
  u16*   qq    = (u16*)  alloc((size_t)MPN * 512 * 2);
  u16*   skipf = (u16*)  alloc((size_t)MPN * 256 * 2);
  u16*   kvbf  = (u16*)  alloc((size_t)MPN * 512 * 2);
  u16*   efp   = (u16*)  alloc((size_t)MPE * 256 * 2);
  int*   offs  = (int*)  alloc((size_t)(NN + 1) * 4);
  int*   cursor= (int*)  alloc((size_t)NN * 4);
  int*   eids  = (int*)  alloc((size_t)EE * 4);
  int*   eidp  = (int*)  alloc((size_t)MPE * 4);
  int*   srcp  = (int*)  alloc((size_t)EE * 4);
  u16*   accv  = (u16*)  alloc((size_t)MPN * 256 * 2);
  u16*   aggef = (u16*)  alloc((size_t)MPN * 256 * 2);
  if(off > ws_size) return;   // workspace too small -> visible validation failure

  // CSR build (deterministic: rank-by-edge-id, no sort)
  csr1_k  <<<1, 1024, 0, stream>>>(dst, offs, cursor);
  scatter_k<<<(EE + 255) / 256, 256, 0, stream>>>(dst, cursor, eids);
  rank_k  <<<(MPE + 255) / 256, 256, 0, stream>>>(dst, src, offs, eids, eidp, srcp);

  // all input/weight conversion in one launch
  prep_all_k<<<PG5, 256, 0, stream>>>(x, eattr, P, Wne, Wee,
      xbf, eabf, Wcat, Wet, WqBF, WeBF, biasc, Wnet, Weet);

  // node encoder + edge encoder + qWe weight GEMMs in one launch
  enc_all_k<<<2672, 256, 0, stream>>>(
      xbf, Wnet, bne, hbf,
      eabf, Weet, bee, efp, eidp,
      WeBF, WqBF, Wcat + (size_t)512 * 256);

  for(int l = 0; l < 3; ++l){
    // fused q|skip|qWe|k|v slab -> qq bf16 + skipf fp16 + kv bf16
    slab_k<<<dim3(MPN / 128, 10), 256, 0, stream>>>(
        hbf, Wcat + (size_t)l * 1280 * 256, biasc + (size_t)l * 1280, qq, kvbf, skipf);
    // per-node attention: scores + exp + weighted sums (pre-divided by denom)
    node_pass_k<<<NN / 4, 256, 0, stream>>>(qq, efp, kvbf, srcp, offs, accv, aggef);
    // out = accv + aggef@We + skip  (+relu, bf16 for layers 0,1; fp32 out for layer 2)
    if(l < 2)
      out3_k<<<dim3(MPN / 128, 2), 256, 0, stream>>>(
          aggef, Wet + (size_t)l * 256 * 256, hbf, accv, skipf);
    else
      out4_k<<<dim3(MPN / 128, 2), 256, 0, stream>>>(
          aggef, Wet + (size_t)l * 256 * 256, (float*)d_out, accv, skipf);
  }
}

// Round 10
// 388.312 us; speedup vs baseline: 1.0663x; 1.0663x over previous
//
#include <hip/hip_runtime.h>
#include <cstdint>

typedef unsigned short u16;
typedef __attribute__((ext_vector_type(8))) short short8;
typedef __attribute__((ext_vector_type(8))) __bf16 bf16x8;
typedef __attribute__((ext_vector_type(4))) float f32x4;

#define DEV __device__ __forceinline__

DEV u16 f2bf(float f){
  uint32_t u = __float_as_uint(f);
  u += 0x7fffu + ((u >> 16) & 1u);
  return (u16)(u >> 16);
}
DEV float bf2f(u16 h){ return __uint_as_float(((uint32_t)h) << 16); }
DEV u16 f2h(float f){ return __builtin_bit_cast(u16, (_Float16)f); }
DEV float h2f(u16 h){ return (float)__builtin_bit_cast(_Float16, h); }

DEV f32x4 mfma16(short8 a, short8 b, f32x4 c){
  return __builtin_amdgcn_mfma_f32_16x16x32_bf16(
      __builtin_bit_cast(bf16x8, a), __builtin_bit_cast(bf16x8, b), c, 0, 0, 0);
}

#define NN 10000
#define EE 160000
#define MPN 10112   /* 79*128  */
#define MPE 160128  /* 1251*128 */

// ---------------- CSR build ----------------
__global__ void count_k(const int* __restrict__ dst, int* __restrict__ cnt){
  int i = blockIdx.x * 256 + threadIdx.x;
  if(i < EE) atomicAdd(&cnt[dst[i]], 1);
}

// single-block scan of the 10000 counts (reads only 40KB -> cheap on one CU)
__global__ __launch_bounds__(1024) void scan_k(const int* __restrict__ cnt,
                                               int* __restrict__ offs,
                                               int* __restrict__ cursor){
  __shared__ int psum[1024];
  int tid = threadIdx.x;
  int base = tid * 10;
  int loc[10];
  int s = 0;
  #pragma unroll
  for(int j = 0; j < 10; ++j){
    int idx = base + j;
    int v = (idx < NN) ? cnt[idx] : 0;
    loc[j] = s; s += v;
  }
  psum[tid] = s;
  __syncthreads();
  for(int d = 1; d < 1024; d <<= 1){
    int t = (tid >= d) ? psum[tid - d] : 0;
    __syncthreads();
    psum[tid] += t;
    __syncthreads();
  }
  int add = (tid > 0) ? psum[tid - 1] : 0;
  #pragma unroll
  for(int j = 0; j < 10; ++j){
    int idx = base + j;
    if(idx < NN){ int v = loc[j] + add; offs[idx] = v; cursor[idx] = v; }
  }
  if(tid == 0) offs[NN] = EE;
}

__global__ void scatter_k(const int* __restrict__ dst, int* __restrict__ cursor,
                          int* __restrict__ eids){
  int i = blockIdx.x * 256 + threadIdx.x;
  if(i < EE){ int p = atomicAdd(&cursor[dst[i]], 1); eids[p] = i; }
}

// deterministic rank: slot(e) = offs[dst] + #{e' in bucket : e' < e}
__global__ void rank_k(const int* __restrict__ dst, const int* __restrict__ src,
                       const int* __restrict__ offs, const int* __restrict__ eids,
                       int* __restrict__ eidp, int* __restrict__ srcp){
  int e = blockIdx.x * 256 + threadIdx.x;
  if(e >= MPE) return;
  if(e >= EE){ eidp[e] = e; return; }      // pad slots -> zero rows of eabf
  int n = dst[e];
  int p0 = offs[n], p1 = offs[n + 1];
  int rk = 0;
  for(int p = p0; p < p1; ++p) rk += (eids[p] < e) ? 1 : 0;
  int slot = p0 + rk;
  eidp[slot] = e;
  srcp[slot] = src[e];
}

// ---------------- weight / input prep (single fused kernel) ----------------
struct WPack {
  const float* Wq[3]; const float* Wk[3]; const float* Wv[3];
  const float* Ws[3]; const float* We[3];
  const float* bq[3]; const float* bk[3]; const float* bv[3]; const float* bs[3];
};

#define PG0 5056                 /* xbf   : MPN*128/256 */
#define PG1 (PG0 + 20016)        /* eabf  : MPE*32/256  */
#define PG2 (PG1 + 3840)         /* Wcat/Wet : 3*1280   */
#define PG3 (PG2 + 1536)         /* WqBF/WeBF: 3*512    */
#define PG4 (PG3 + 15)           /* biasc */
#define PG5 (PG4 + 256)          /* encoders */

// Wcat rows per layer: [0,256) Wq^T | [256,512) Ws^T | [512,768) qWe (GEMM EPI5)
//                      | [768,1024) Wk^T | [1024,1280) Wv^T
__global__ __launch_bounds__(256) void prep_all_k(
    const float* __restrict__ x, const float* __restrict__ eattr, WPack P,
    const float* __restrict__ Wne, const float* __restrict__ Wee,
    u16* __restrict__ xbf, u16* __restrict__ eabf,
    u16* __restrict__ Wcat, u16* __restrict__ Wet,
    u16* __restrict__ WqBF, u16* __restrict__ WeBF,
    float* __restrict__ biasc, u16* __restrict__ Wnet, u16* __restrict__ Weet)
{
  int b = blockIdx.x, tid = threadIdx.x;
  if(b < PG0){
    int i = b * 256 + tid;
    xbf[i] = (i < NN * 128) ? f2bf(x[i]) : (u16)0;
  } else if(b < PG1){
    int i = (b - PG0) * 256 + tid;
    eabf[i] = (i < EE * 32) ? f2bf(eattr[i]) : (u16)0;
  } else if(b < PG2){
    int b2 = b - PG1; int l = b2 / 1280, r = b2 % 1280; int k = tid;
    float v;
    if(r < 256)       v = P.Wq[l][k * 256 + r];
    else if(r < 512)  v = P.Ws[l][k * 256 + (r - 256)];
    else if(r < 768){ Wet[((size_t)l * 256 + (r - 512)) * 256 + k] =
                        f2bf(P.We[l][k * 256 + (r - 512)]); return; }
    else if(r < 1024) v = P.Wk[l][k * 256 + (r - 768)];
    else              v = P.Wv[l][k * 256 + (r - 1024)];
    Wcat[((size_t)l * 1280 + r) * 256 + k] = f2bf(v);
  } else if(b < PG3){
    int b3 = b - PG2; int l = b3 >> 9, rr = b3 & 511; int t = tid;
    if(rr < 256) WqBF[((size_t)l * 256 + rr) * 256 + t] = f2bf(P.Wq[l][rr * 256 + t]);
    else         WeBF[((size_t)l * 256 + (rr - 256)) * 256 + t] = f2bf(P.We[l][(rr - 256) * 256 + t]);
  } else if(b < PG4){
    int b4 = b - PG3; int l = b4 / 5, seg = b4 % 5; int t = tid;
    float v;
    if(seg == 0)      v = P.bq[l][t];
    else if(seg == 1) v = P.bs[l][t];
    else if(seg == 2){
      const float* we = P.We[l] + (size_t)t * 256; const float* bq = P.bq[l];
      float s = 0.f;
      for(int c = 0; c < 256; ++c) s += bq[c] * we[c];
      v = s;
    }
    else if(seg == 3) v = P.bk[l][t];
    else              v = P.bv[l][t];
    biasc[(size_t)l * 1280 + seg * 256 + t] = v;
  } else {
    int n = b - PG4;
    if(tid < 128) Wnet[n * 128 + tid] = f2bf(Wne[(size_t)tid * 256 + n]);
    if(tid < 32)  Weet[n * 32 + tid]  = f2bf(Wee[(size_t)tid * 256 + n]);
  }
}

// ---------------- MFMA GEMM body:  C[M,N] = A[M,K](bf16) @ Bt[N,K]^T(bf16) ----------------
// AG: gather A rows through rowmap.
// EPI 0: +bias; sec(by/2): 0 q->Out(ld512) | 1 skip->skipOut fp16(ld256)
//        | 2 qWe->Out(+256) | 3 k->kvout | 4 v->kvout(+256)
// EPI 1: +bias, relu -> bf16 (Out, ld Nld)
// EPI 3: acc + accv(fp16) + skip(fp16), relu -> bf16
// EPI 4: acc + accv(fp16) + skip(fp16) -> fp32
// EPI 5: plain -> bf16 (weight-prep GEMM; batched over bz)
template<int BK, int EPI, int AG>
DEV void gemm_body(short8* smem8,
    const u16* __restrict__ A, const u16* __restrict__ Bt,
    const float* __restrict__ bias, void* Out,
    const u16* __restrict__ accvH, const u16* __restrict__ skipH,
    const int* __restrict__ rowmap, u16* __restrict__ kvout,
    u16* __restrict__ skipOut,
    int bx, int by, int bz,
    int Mreal, int Nld, int K, size_t sA, size_t sB, size_t sOb)
{
  constexpr int CPR = BK / 8;           // 16B chunks per LDS row
  constexpr int SW  = (BK == 64) ? 7 : 3;
  u16* Al = (u16*)smem8;
  u16* Bl = Al + 128 * BK;
  A  += (size_t)bz * sA;
  Bt += (size_t)bz * sB;
  Out = (void*)((char*)Out + (size_t)bz * sOb);
  int tid = threadIdx.x, lane = tid & 63;
  int rowBase = bx * 128, colBase = by * 128;
  int wave = tid >> 6, wm = wave >> 1, wn = wave & 1;
  int lr = lane & 15, lk = lane >> 4;
  f32x4 acc[4][4] = {};
  int nkt = K / BK;
  for(int kt = 0; kt < nkt; ++kt){
    __syncthreads();
    for(int ci = tid; ci < 128 * CPR; ci += 256){
      int r = ci / CPR, cb = ci % CPR;
      int ar = AG ? rowmap[rowBase + r] : (rowBase + r);
      int d = (r * CPR + (cb ^ (r & SW))) * 8;     // swizzled dest (u16 units)
      *(short8*)&Al[d] = *(const short8*)&A [(size_t)ar * K + kt * BK + cb * 8];
      *(short8*)&Bl[d] = *(const short8*)&Bt[(size_t)(colBase + r) * K + kt * BK + cb * 8];
    }
    __syncthreads();
    #pragma unroll
    for(int kk = 0; kk < BK / 32; ++kk){
      short8 af[4], bfr[4];
      #pragma unroll
      for(int m = 0; m < 4; ++m){
        int r = wm * 64 + m * 16 + lr;
        int byt = r * (BK * 2) + kk * 64 + lk * 16; byt ^= (r & SW) << 4;
        af[m] = *(const short8*)((const char*)Al + byt);
      }
      #pragma unroll
      for(int n = 0; n < 4; ++n){
        int r = wn * 64 + n * 16 + lr;
        int byt = r * (BK * 2) + kk * 64 + lk * 16; byt ^= (r & SW) << 4;
        bfr[n] = *(const short8*)((const char*)Bl + byt);
      }
      #pragma unroll
      for(int m = 0; m < 4; ++m)
        #pragma unroll
        for(int n = 0; n < 4; ++n)
          acc[m][n] = mfma16(af[m], bfr[n], acc[m][n]);
    }
  }

  // ---------- epilogue: LDS-staged, vectorized 16B stores ----------
  __syncthreads();                       // all ds_reads done before LDS reuse
  if constexpr(EPI == 4){
    float* fs = (float*)smem8;           // [64][128] fp32, two passes
    #pragma unroll
    for(int h = 0; h < 2; ++h){
      if(wm == h){
        #pragma unroll
        for(int m = 0; m < 4; ++m)
          #pragma unroll
          for(int n = 0; n < 4; ++n){
            int cc = wn * 64 + n * 16 + lr;
            int c = colBase + cc;
            #pragma unroll
            for(int j = 0; j < 4; ++j){
              int r2 = m * 16 + lk * 4 + j;
              int r = rowBase + h * 64 + r2;
              fs[r2 * 128 + cc] = acc[m][n][j]
                + h2f(accvH[(size_t)r * 256 + c]) + h2f(skipH[(size_t)r * 256 + c]);
            }
          }
      }
      __syncthreads();
      for(int ch = tid; ch < 2048; ch += 256){
        int rr = ch >> 5, cc = (ch & 31) << 2;
        int r = rowBase + h * 64 + rr;
        if(r < Mreal)
          *(float4*)&((float*)Out)[(size_t)r * Nld + colBase + cc] = *(float4*)&fs[rr * 128 + cc];
      }
      __syncthreads();
    }
  } else if constexpr(EPI == 0){
    int sec = by >> 1;                   // 0 q | 1 skip | 2 qWe | 3 k | 4 v
    u16* us = (u16*)smem8;               // [128][128] u16 (bf16 or fp16)
    #pragma unroll
    for(int m = 0; m < 4; ++m)
      #pragma unroll
      for(int n = 0; n < 4; ++n){
        int cc = wn * 64 + n * 16 + lr;
        #pragma unroll
        for(int j = 0; j < 4; ++j){
          int rr = wm * 64 + m * 16 + lk * 4 + j;
          float v = acc[m][n][j] + bias[colBase + cc];
          us[rr * 128 + cc] = (sec == 1) ? f2h(v) : f2bf(v);
        }
      }
    __syncthreads();
    u16* dstp; int cofs, ldd;
    if(sec == 0){ dstp = (u16*)Out; cofs = colBase; ldd = 512; }
    else if(sec == 1){ dstp = skipOut; cofs = colBase - 256; ldd = 256; }
    else if(sec == 2){ dstp = (u16*)Out; cofs = colBase - 256; ldd = 512; }
    else { dstp = kvout; cofs = colBase - 768; ldd = 512; }
    for(int ch = tid; ch < 2048; ch += 256){
      int rr = ch >> 4, cc = (ch & 15) << 3;
      int r = rowBase + rr;
      if(r < Mreal)
        *(short8*)&dstp[(size_t)r * ldd + cofs + cc] = *(short8*)&us[rr * 128 + cc];
    }
  } else {
    // bf16 single-pass: EPI 1 (bias+relu), 3 (accv+skip+relu), 5 (plain)
    u16* us = (u16*)smem8;               // [128][128] bf16
    #pragma unroll
    for(int m = 0; m < 4; ++m)
      #pragma unroll
      for(int n = 0; n < 4; ++n){
        int cc = wn * 64 + n * 16 + lr;
        int c = colBase + cc;
        #pragma unroll
        for(int j = 0; j < 4; ++j){
          int rr = wm * 64 + m * 16 + lk * 4 + j;
          float v = acc[m][n][j];
          if constexpr(EPI == 1){ v += bias[c]; v = fmaxf(v, 0.f); }
          else if constexpr(EPI == 3){
            int r = rowBase + rr;
            v += h2f(accvH[(size_t)r * 256 + c]) + h2f(skipH[(size_t)r * 256 + c]);
            v = fmaxf(v, 0.f);
          }
          us[rr * 128 + cc] = f2bf(v);
        }
      }
    __syncthreads();
    for(int ch = tid; ch < 2048; ch += 256){
      int rr = ch >> 4, cc = (ch & 15) << 3;
      int r = rowBase + rr;
      if(r < Mreal)
        *(short8*)&((u16*)Out)[(size_t)r * Nld + colBase + cc] = *(short8*)&us[rr * 128 + cc];
    }
  }
}

// ---------------- GEMM kernel wrappers ----------------
__global__ __launch_bounds__(256) void slab_k(
    const u16* __restrict__ A, const u16* __restrict__ Bt,
    const float* __restrict__ bias, u16* __restrict__ qq,
    u16* __restrict__ kvout, u16* __restrict__ skipOut){
  __shared__ short8 smem[2048];
  gemm_body<64,0,0>(smem, A, Bt, bias, qq, nullptr, nullptr, nullptr, kvout, skipOut,
                    blockIdx.x, blockIdx.y, 0, NN, 512, 256, 0, 0, 0);
}

__global__ __launch_bounds__(256) void out3_k(
    const u16* __restrict__ A, const u16* __restrict__ Bt, u16* __restrict__ Out,
    const u16* __restrict__ accvH, const u16* __restrict__ skipH){
  __shared__ short8 smem[2048];
  gemm_body<64,3,0>(smem, A, Bt, nullptr, Out, accvH, skipH, nullptr, nullptr, nullptr,
                    blockIdx.x, blockIdx.y, 0, NN, 256, 256, 0, 0, 0);
}

__global__ __launch_bounds__(256) void out4_k(
    const u16* __restrict__ A, const u16* __restrict__ Bt, float* __restrict__ Out,
    const u16* __restrict__ accvH, const u16* __restrict__ skipH){
  __shared__ short8 smem[2048];
  gemm_body<64,4,0>(smem, A, Bt, nullptr, Out, accvH, skipH, nullptr, nullptr, nullptr,
                    blockIdx.x, blockIdx.y, 0, NN, 256, 256, 0, 0, 0);
}

// node-enc (158 blocks) + edge-enc (2502) + weight GEMMs (12) in one launch
__global__ __launch_bounds__(256) void enc_all_k(
    const u16* __restrict__ xbf, const u16* __restrict__ Wnet,
    const float* __restrict__ bne, u16* __restrict__ hbf,
    const u16* __restrict__ eabf, const u16* __restrict__ Weet,
    const float* __restrict__ bee, u16* __restrict__ efp, const int* __restrict__ eidp,
    const u16* __restrict__ WeBF, const u16* __restrict__ WqBF, u16* __restrict__ WcatQ){
  __shared__ short8 smem[2048];
  int b = blockIdx.x;
  if(b < 158){
    gemm_body<64,1,0>(smem, xbf, Wnet, bne, hbf, nullptr, nullptr, nullptr, nullptr, nullptr,
                      b >> 1, b & 1, 0, NN, 256, 128, 0, 0, 0);
  } else if(b < 2660){
    int bb = b - 158;
    gemm_body<32,1,1>(smem, eabf, Weet, bee, efp, nullptr, nullptr, eidp, nullptr, nullptr,
                      bb >> 1, bb & 1, 0, EE, 256, 32, 0, 0, 0);
  } else {
    int bb = b - 2660;   // 12 blocks: bx = bb&1, by = (bb>>1)&1, bz = bb>>2
    gemm_body<64,5,0>(smem, WeBF, WqBF, nullptr, WcatQ, nullptr, nullptr, nullptr, nullptr, nullptr,
                      bb & 1, (bb >> 1) & 1, bb >> 2, 256, 256, 256,
                      (size_t)256 * 256, (size_t)256 * 256, (size_t)1280 * 256 * 2);
  }
}

// ---------------- fused per-node attention pass ----------------
// qq row (ld 512 bf16): q[0:256) qWe[256:512)
// kvbf row (ld 512 bf16): k[0:256) v[256:512)
// efp row (ld 256 bf16): edge features in CSR slot order
// ONE node per WAVE; per 64-edge window, group eg owns edges [t*64+eg*16,+16):
// each group loads its OWN srcp slice and broadcasts GROUP-LOCALLY (gb+j) —
// cross-group __shfl under divergent exec reads inactive lanes (returns 0) and
// was the R6/R8 0.481 bug. accv/agg written fp16/bf16.
__global__ __launch_bounds__(256) void node_pass_k(
    const u16* __restrict__ qq, const u16* __restrict__ efp,
    const u16* __restrict__ kvbf,
    const int* __restrict__ srcp, const int* __restrict__ offs,
    u16* __restrict__ accvH, u16* __restrict__ aggef)
{
  int wave = threadIdx.x >> 6, lane = threadIdx.x & 63;
  int n = blockIdx.x * 4 + wave;
  if(n >= NN) return;
  int li = lane & 15, eg = lane >> 4, gb = lane & 48;
  const u16* qrow = qq + (size_t)n * 512 + li * 16;
  short8 qh0 = *(const short8*)(qrow),       qh1 = *(const short8*)(qrow + 8);
  short8 eh0 = *(const short8*)(qrow + 256), eh1 = *(const short8*)(qrow + 264);
  float q[16], e[16];
  #pragma unroll
  for(int d = 0; d < 8; ++d){
    q[d] = bf2f((u16)qh0[d]); q[8 + d] = bf2f((u16)qh1[d]);
    e[d] = bf2f((u16)eh0[d]); e[8 + d] = bf2f((u16)eh1[d]);
  }
  float av[16], ag[16];
  #pragma unroll
  for(int d = 0; d < 16; ++d){ av[d] = 0.f; ag[d] = 0.f; }
  float den = 0.f;
  int p0 = offs[n], deg = offs[n + 1] - p0;
  int nwin = (deg + 63) >> 6;                       // uniform across the wave
  for(int t = 0; t < nwin; ++t){
    int gstart = t * 64 + eg * 16;                  // this group's sub-window
    int rem = deg - gstart;
    int scnt = rem < 16 ? (rem < 0 ? 0 : rem) : 16;
    int ssrc = (li < scnt) ? srcp[p0 + gstart + li] : 0;  // group-local 16-read
    int jj = 0;
    for(; jj + 1 < scnt; jj += 2){
      int s1 = __shfl(ssrc, gb + jj);               // group-local broadcast
      int s2 = __shfl(ssrc, gb + jj + 1);
      size_t pp = (size_t)(p0 + gstart + jj);
      const u16* kv1 = kvbf + ((size_t)s1 << 9) + li * 16;
      const u16* kv2 = kvbf + ((size_t)s2 << 9) + li * 16;
      const u16* e1 = efp + (pp << 8) + li * 16;
      const u16* e2 = efp + ((pp + 1) << 8) + li * 16;
      short8 kA1 = *(const short8*)(kv1),       kB1 = *(const short8*)(kv1 + 8);
      short8 vA1 = *(const short8*)(kv1 + 256), vB1 = *(const short8*)(kv1 + 264);
      short8 fA1 = *(const short8*)(e1),        fB1 = *(const short8*)(e1 + 8);
      short8 kA2 = *(const short8*)(kv2),       kB2 = *(const short8*)(kv2 + 8);
      short8 vA2 = *(const short8*)(kv2 + 256), vB2 = *(const short8*)(kv2 + 264);
      short8 fA2 = *(const short8*)(e2),        fB2 = *(const short8*)(e2 + 8);
      float sc1 = 0.f, sc2 = 0.f;
      #pragma unroll
      for(int d = 0; d < 8; ++d){
        sc1 += q[d]   * bf2f((u16)kA1[d]) + e[d]   * bf2f((u16)fA1[d]);
        sc1 += q[8+d] * bf2f((u16)kB1[d]) + e[8+d] * bf2f((u16)fB1[d]);
        sc2 += q[d]   * bf2f((u16)kA2[d]) + e[d]   * bf2f((u16)fA2[d]);
        sc2 += q[8+d] * bf2f((u16)kB2[d]) + e[8+d] * bf2f((u16)fB2[d]);
      }
      sc1 += __shfl_xor(sc1, 1); sc2 += __shfl_xor(sc2, 1);
      sc1 += __shfl_xor(sc1, 2); sc2 += __shfl_xor(sc2, 2);
      sc1 += __shfl_xor(sc1, 4); sc2 += __shfl_xor(sc2, 4);
      sc1 += __shfl_xor(sc1, 8); sc2 += __shfl_xor(sc2, 8);
      float w1 = __expf(sc1 * 0.0625f);
      float w2 = __expf(sc2 * 0.0625f);
      den += w1 + w2;
      #pragma unroll
      for(int d = 0; d < 8; ++d){
        av[d]   += w1 * bf2f((u16)vA1[d]) + w2 * bf2f((u16)vA2[d]);
        av[8+d] += w1 * bf2f((u16)vB1[d]) + w2 * bf2f((u16)vB2[d]);
        ag[d]   += w1 * bf2f((u16)fA1[d]) + w2 * bf2f((u16)fA2[d]);
        ag[8+d] += w1 * bf2f((u16)fB1[d]) + w2 * bf2f((u16)fB2[d]);
      }
    }
    if(jj < scnt){
      int s = __shfl(ssrc, gb + jj);                // group-local broadcast
      size_t pp = (size_t)(p0 + gstart + jj);
      const u16* kvp = kvbf + ((size_t)s << 9) + li * 16;
      const u16* ep = efp + (pp << 8) + li * 16;
      short8 kA = *(const short8*)(kvp),       kB = *(const short8*)(kvp + 8);
      short8 vA = *(const short8*)(kvp + 256), vB = *(const short8*)(kvp + 264);
      short8 fA = *(const short8*)(ep),        fB = *(const short8*)(ep + 8);
      float part = 0.f;
      #pragma unroll
      for(int d = 0; d < 8; ++d){
        part += q[d]   * bf2f((u16)kA[d]) + e[d]   * bf2f((u16)fA[d]);
        part += q[8+d] * bf2f((u16)kB[d]) + e[8+d] * bf2f((u16)fB[d]);
      }
      part += __shfl_xor(part, 1);
      part += __shfl_xor(part, 2);
      part += __shfl_xor(part, 4);
      part += __shfl_xor(part, 8);
      float wgt = __expf(part * 0.0625f);
      den += wgt;
      #pragma unroll
      for(int d = 0; d < 8; ++d){
        av[d]   += wgt * bf2f((u16)vA[d]);
        av[8+d] += wgt * bf2f((u16)vB[d]);
        ag[d]   += wgt * bf2f((u16)fA[d]);
        ag[8+d] += wgt * bf2f((u16)fB[d]);
      }
    }
  }
  // combine the 4 edge-groups (convergent — all 64 lanes active here)
  #pragma unroll
  for(int d = 0; d < 16; ++d){
    av[d] += __shfl_xor(av[d], 16); av[d] += __shfl_xor(av[d], 32);
    ag[d] += __shfl_xor(ag[d], 16); ag[d] += __shfl_xor(ag[d], 32);
  }
  den += __shfl_xor(den, 16); den += __shfl_xor(den, 32);
  float rden = 1.f / fmaxf(den, 1e-16f);          // pre-divide (linear in We)
  if(eg == 0){
    u16* ao = accvH + (size_t)n * 256 + li * 16;
    #pragma unroll
    for(int t = 0; t < 2; ++t){
      short8 o;
      #pragma unroll
      for(int d = 0; d < 8; ++d) o[d] = (short)f2h(av[t*8+d] * rden);
      *(short8*)(ao + t * 8) = o;
    }
  } else if(eg == 1){
    u16* go = aggef + (size_t)n * 256 + li * 16;
    #pragma unroll
    for(int t = 0; t < 2; ++t){
      short8 o;
      #pragma unroll
      for(int d = 0; d < 8; ++d) o[d] = (short)f2bf(ag[t*8+d] * rden);
      *(short8*)(go + t * 8) = o;
    }
  }
}

// ---------------- launch ----------------
extern "C" void kernel_launch(void* const* d_in, const int* in_sizes, int n_in,
                              void* d_out, int out_size, void* d_ws, size_t ws_size,
                              hipStream_t stream){
  const float* x     = (const float*)d_in[0];
  const float* eattr = (const float*)d_in[1];
  const int*   src   = (const int*)d_in[2];
  const int*   dst   = (const int*)d_in[3];
  const float* Wee   = (const float*)d_in[4];
  const float* bee   = (const float*)d_in[5];
  const float* Wne   = (const float*)d_in[6];
  const float* bne   = (const float*)d_in[7];
  WPack P;
  for(int l = 0; l < 3; ++l){
    const int b = 8 + l * 9;
    P.Wq[l] = (const float*)d_in[b + 0]; P.bq[l] = (const float*)d_in[b + 1];
    P.Wk[l] = (const float*)d_in[b + 2]; P.bk[l] = (const float*)d_in[b + 3];
    P.Wv[l] = (const float*)d_in[b + 4]; P.bv[l] = (const float*)d_in[b + 5];
    P.We[l] = (const float*)d_in[b + 6];
    P.Ws[l] = (const float*)d_in[b + 7]; P.bs[l] = (const float*)d_in[b + 8];
  }

  char* w = (char*)d_ws; size_t off = 0;
  auto alloc = [&](size_t bytes)->char*{
    char* p = w + off; off = (off + bytes + 255) & ~(size_t)255; return p;
  };
  u16*   Wcat  = (u16*)  alloc((size_t)3 * 1280 * 256 * 2);
  u16*   Wet   = (u16*)  alloc((size_t)3 * 256 * 256 * 2);
  u16*   WqBF  = (u16*)  alloc((size_t)3 * 256 * 256 * 2);
  u16*   WeBF  = (u16*)  alloc((size_t)3 * 256 * 256 * 2);
  float* biasc = (float*)alloc((size_t)3 * 1280 * 4);
  u16*   Wnet  = (u16*)  alloc((size_t)256 * 128 * 2);
  u16*   Weet  = (u16*)  alloc((size_t)256 * 32 * 2);
  u16*   xbf   = (u16*)  alloc((size_t)MPN * 128 * 2);
  u16*   eabf  = (u16*)  alloc((size_t)MPE * 32 * 2);
  u16*   hbf   = (u16*)  alloc((size_t)MPN * 256 * 2);
  u16*   qq    = (u16*)  alloc((size_t)MPN * 512 * 2);
  u16*   skipf = (u16*)  alloc((size_t)MPN * 256 * 2);
  u16*   kvbf  = (u16*)  alloc((size_t)MPN * 512 * 2);
  u16*   efp   = (u16*)  alloc((size_t)MPE * 256 * 2);
  int*   cnt   = (int*)  alloc((size_t)NN * 4);
  int*   offs  = (int*)  alloc((size_t)(NN + 1) * 4);
  int*   cursor= (int*)  alloc((size_t)NN * 4);
  int*   eids  = (int*)  alloc((size_t)EE * 4);
  int*   eidp  = (int*)  alloc((size_t)MPE * 4);
  int*   srcp  = (int*)  alloc((size_t)EE * 4);
  u16*   accv  = (u16*)  alloc((size_t)MPN * 256 * 2);
  u16*   aggef = (u16*)  alloc((size_t)MPN * 256 * 2);
  if(off > ws_size) return;   // workspace too small -> visible validation failure

  // CSR build (deterministic: rank-by-edge-id, no sort)
  hipMemsetAsync(cnt, 0, (size_t)NN * 4, stream);
  count_k <<<(EE + 255) / 256, 256, 0, stream>>>(dst, cnt);
  scan_k  <<<1, 1024, 0, stream>>>(cnt, offs, cursor);
  scatter_k<<<(EE + 255) / 256, 256, 0, stream>>>(dst, cursor, eids);
  rank_k  <<<(MPE + 255) / 256, 256, 0, stream>>>(dst, src, offs, eids, eidp, srcp);

  // all input/weight conversion in one launch
  prep_all_k<<<PG5, 256, 0, stream>>>(x, eattr, P, Wne, Wee,
      xbf, eabf, Wcat, Wet, WqBF, WeBF, biasc, Wnet, Weet);

  // node encoder + edge encoder + qWe weight GEMMs in one launch
  enc_all_k<<<2672, 256, 0, stream>>>(
      xbf, Wnet, bne, hbf,
      eabf, Weet, bee, efp, eidp,
      WeBF, WqBF, Wcat + (size_t)512 * 256);

  for(int l = 0; l < 3; ++l){
    // fused q|skip|qWe|k|v slab -> qq bf16 + skipf fp16 + kv bf16
    slab_k<<<dim3(MPN / 128, 10), 256, 0, stream>>>(
        hbf, Wcat + (size_t)l * 1280 * 256, biasc + (size_t)l * 1280, qq, kvbf, skipf);
    // per-node attention: scores + exp + weighted sums (pre-divided by denom)
    node_pass_k<<<NN / 4, 256, 0, stream>>>(qq, efp, kvbf, srcp, offs, accv, aggef);
    // out = accv + aggef@We + skip  (+relu, bf16 for layers 0,1; fp32 out for layer 2)
    if(l < 2)
      out3_k<<<dim3(MPN / 128, 2), 256, 0, stream>>>(
          aggef, Wet + (size_t)l * 256 * 256, hbf, accv, skipf);
    else
      out4_k<<<dim3(MPN / 128, 2), 256, 0, stream>>>(
          aggef, Wet + (size_t)l * 256 * 256, (float*)d_out, accv, skipf);
  }
}

// Round 11
// 338.569 us; speedup vs baseline: 1.2229x; 1.1469x over previous
//
#include <hip/hip_runtime.h>
#include <cstdint>

typedef unsigned short u16;
typedef __attribute__((ext_vector_type(8))) short short8;
typedef __attribute__((ext_vector_type(8))) __bf16 bf16x8;
typedef __attribute__((ext_vector_type(4))) float f32x4;

#define DEV __device__ __forceinline__

DEV u16 f2bf(float f){
  uint32_t u = __float_as_uint(f);
  u += 0x7fffu + ((u >> 16) & 1u);
  return (u16)(u >> 16);
}
DEV float bf2f(u16 h){ return __uint_as_float(((uint32_t)h) << 16); }
DEV u16 f2h(float f){ return __builtin_bit_cast(u16, (_Float16)f); }
DEV float h2f(u16 h){ return (float)__builtin_bit_cast(_Float16, h); }

DEV f32x4 mfma16(short8 a, short8 b, f32x4 c){
  return __builtin_amdgcn_mfma_f32_16x16x32_bf16(
      __builtin_bit_cast(bf16x8, a), __builtin_bit_cast(bf16x8, b), c, 0, 0, 0);
}

#define NN 10000
#define EE 160000
#define MPN 10112   /* 79*128  */
#define MPE 160128  /* 1251*128 */

// ---------------- CSR build ----------------
__global__ void count_k(const int* __restrict__ dst, int* __restrict__ cnt){
  int i = blockIdx.x * 256 + threadIdx.x;
  if(i < EE) atomicAdd(&cnt[dst[i]], 1);
}

// single-block scan of the 10000 counts (reads only 40KB -> cheap on one CU)
__global__ __launch_bounds__(1024) void scan_k(const int* __restrict__ cnt,
                                               int* __restrict__ offs,
                                               int* __restrict__ cursor){
  __shared__ int psum[1024];
  int tid = threadIdx.x;
  int base = tid * 10;
  int loc[10];
  int s = 0;
  #pragma unroll
  for(int j = 0; j < 10; ++j){
    int idx = base + j;
    int v = (idx < NN) ? cnt[idx] : 0;
    loc[j] = s; s += v;
  }
  psum[tid] = s;
  __syncthreads();
  for(int d = 1; d < 1024; d <<= 1){
    int t = (tid >= d) ? psum[tid - d] : 0;
    __syncthreads();
    psum[tid] += t;
    __syncthreads();
  }
  int add = (tid > 0) ? psum[tid - 1] : 0;
  #pragma unroll
  for(int j = 0; j < 10; ++j){
    int idx = base + j;
    if(idx < NN){ int v = loc[j] + add; offs[idx] = v; cursor[idx] = v; }
  }
  if(tid == 0) offs[NN] = EE;
}

__global__ void scatter_k(const int* __restrict__ dst, int* __restrict__ cursor,
                          int* __restrict__ eids){
  int i = blockIdx.x * 256 + threadIdx.x;
  if(i < EE){ int p = atomicAdd(&cursor[dst[i]], 1); eids[p] = i; }
}

// deterministic rank: slot(e) = offs[dst] + #{e' in bucket : e' < e}
__global__ void rank_k(const int* __restrict__ dst, const int* __restrict__ src,
                       const int* __restrict__ offs, const int* __restrict__ eids,
                       int* __restrict__ eidp, int* __restrict__ srcp){
  int e = blockIdx.x * 256 + threadIdx.x;
  if(e >= MPE) return;
  if(e >= EE){ eidp[e] = e; return; }      // pad slots -> zero rows of eabf
  int n = dst[e];
  int p0 = offs[n], p1 = offs[n + 1];
  int rk = 0;
  for(int p = p0; p < p1; ++p) rk += (eids[p] < e) ? 1 : 0;
  int slot = p0 + rk;
  eidp[slot] = e;
  srcp[slot] = src[e];
}

// ---------------- weight / input prep (single fused kernel) ----------------
struct WPack {
  const float* Wq[3]; const float* Wk[3]; const float* Wv[3];
  const float* Ws[3]; const float* We[3];
  const float* bq[3]; const float* bk[3]; const float* bv[3]; const float* bs[3];
};

#define PG0 5056                 /* xbf   : MPN*128/256 */
#define PG1 (PG0 + 20016)        /* eabf  : MPE*32/256  */
#define PG2 (PG1 + 3840)         /* Wcat/Wet : 3*1280   */
#define PG3 (PG2 + 1536)         /* WqBF/WeBF: 3*512    */
#define PG4 (PG3 + 15)           /* biasc */
#define PG5 (PG4 + 256)          /* encoders */

// Wcat rows per layer: [0,256) Wq^T | [256,512) Ws^T | [512,768) qWe (GEMM EPI5)
//                      | [768,1024) Wk^T | [1024,1280) Wv^T
__global__ __launch_bounds__(256) void prep_all_k(
    const float* __restrict__ x, const float* __restrict__ eattr, WPack P,
    const float* __restrict__ Wne, const float* __restrict__ Wee,
    u16* __restrict__ xbf, u16* __restrict__ eabf,
    u16* __restrict__ Wcat, u16* __restrict__ Wet,
    u16* __restrict__ WqBF, u16* __restrict__ WeBF,
    float* __restrict__ biasc, u16* __restrict__ Wnet, u16* __restrict__ Weet)
{
  int b = blockIdx.x, tid = threadIdx.x;
  if(b < PG0){
    int i = b * 256 + tid;
    xbf[i] = (i < NN * 128) ? f2bf(x[i]) : (u16)0;
  } else if(b < PG1){
    int i = (b - PG0) * 256 + tid;
    eabf[i] = (i < EE * 32) ? f2bf(eattr[i]) : (u16)0;
  } else if(b < PG2){
    int b2 = b - PG1; int l = b2 / 1280, r = b2 % 1280; int k = tid;
    float v;
    if(r < 256)       v = P.Wq[l][k * 256 + r];
    else if(r < 512)  v = P.Ws[l][k * 256 + (r - 256)];
    else if(r < 768){ Wet[((size_t)l * 256 + (r - 512)) * 256 + k] =
                        f2bf(P.We[l][k * 256 + (r - 512)]); return; }
    else if(r < 1024) v = P.Wk[l][k * 256 + (r - 768)];
    else              v = P.Wv[l][k * 256 + (r - 1024)];
    Wcat[((size_t)l * 1280 + r) * 256 + k] = f2bf(v);
  } else if(b < PG3){
    int b3 = b - PG2; int l = b3 >> 9, rr = b3 & 511; int t = tid;
    if(rr < 256) WqBF[((size_t)l * 256 + rr) * 256 + t] = f2bf(P.Wq[l][rr * 256 + t]);
    else         WeBF[((size_t)l * 256 + (rr - 256)) * 256 + t] = f2bf(P.We[l][(rr - 256) * 256 + t]);
  } else if(b < PG4){
    int b4 = b - PG3; int l = b4 / 5, seg = b4 % 5; int t = tid;
    float v;
    if(seg == 0)      v = P.bq[l][t];
    else if(seg == 1) v = P.bs[l][t];
    else if(seg == 2){
      const float* we = P.We[l] + (size_t)t * 256; const float* bq = P.bq[l];
      float s = 0.f;
      for(int c = 0; c < 256; ++c) s += bq[c] * we[c];
      v = s;
    }
    else if(seg == 3) v = P.bk[l][t];
    else              v = P.bv[l][t];
    biasc[(size_t)l * 1280 + seg * 256 + t] = v;
  } else {
    int n = b - PG4;
    if(tid < 128) Wnet[n * 128 + tid] = f2bf(Wne[(size_t)tid * 256 + n]);
    if(tid < 32)  Weet[n * 32 + tid]  = f2bf(Wee[(size_t)tid * 256 + n]);
  }
}

// ---------------- MFMA GEMM body:  C[M,N] = A[M,K](bf16) @ Bt[N,K]^T(bf16) ----------------
// AG: gather A rows through rowmap.
// EPI 0: +bias; sec(by/2): 0 q->Out(ld512) | 1 skip->skipOut fp16(ld256)
//        | 2 qWe->Out(+256) | 3 k->kvout | 4 v->kvout(+256)
// EPI 1: +bias, relu -> bf16 (Out, ld Nld)
// EPI 3: acc + accv(fp16) + skip(fp16), relu -> bf16
// EPI 4: acc + accv(fp16) + skip(fp16) -> fp32
// EPI 5: plain -> bf16 (weight-prep GEMM; batched over bz)
template<int BK, int EPI, int AG>
DEV void gemm_body(short8* smem8,
    const u16* __restrict__ A, const u16* __restrict__ Bt,
    const float* __restrict__ bias, void* Out,
    const u16* __restrict__ accvH, const u16* __restrict__ skipH,
    const int* __restrict__ rowmap, u16* __restrict__ kvout,
    u16* __restrict__ skipOut,
    int bx, int by, int bz,
    int Mreal, int Nld, int K, size_t sA, size_t sB, size_t sOb)
{
  constexpr int CPR = BK / 8;           // 16B chunks per LDS row
  constexpr int SW  = (BK == 64) ? 7 : 3;
  u16* Al = (u16*)smem8;
  u16* Bl = Al + 128 * BK;
  A  += (size_t)bz * sA;
  Bt += (size_t)bz * sB;
  Out = (void*)((char*)Out + (size_t)bz * sOb);
  int tid = threadIdx.x, lane = tid & 63;
  int rowBase = bx * 128, colBase = by * 128;
  int wave = tid >> 6, wm = wave >> 1, wn = wave & 1;
  int lr = lane & 15, lk = lane >> 4;
  f32x4 acc[4][4] = {};
  int nkt = K / BK;
  for(int kt = 0; kt < nkt; ++kt){
    __syncthreads();
    for(int ci = tid; ci < 128 * CPR; ci += 256){
      int r = ci / CPR, cb = ci % CPR;
      int ar = AG ? rowmap[rowBase + r] : (rowBase + r);
      int d = (r * CPR + (cb ^ (r & SW))) * 8;     // swizzled dest (u16 units)
      *(short8*)&Al[d] = *(const short8*)&A [(size_t)ar * K + kt * BK + cb * 8];
      *(short8*)&Bl[d] = *(const short8*)&Bt[(size_t)(colBase + r) * K + kt * BK + cb * 8];
    }
    __syncthreads();
    #pragma unroll
    for(int kk = 0; kk < BK / 32; ++kk){
      short8 af[4], bfr[4];
      #pragma unroll
      for(int m = 0; m < 4; ++m){
        int r = wm * 64 + m * 16 + lr;
        int byt = r * (BK * 2) + kk * 64 + lk * 16; byt ^= (r & SW) << 4;
        af[m] = *(const short8*)((const char*)Al + byt);
      }
      #pragma unroll
      for(int n = 0; n < 4; ++n){
        int r = wn * 64 + n * 16 + lr;
        int byt = r * (BK * 2) + kk * 64 + lk * 16; byt ^= (r & SW) << 4;
        bfr[n] = *(const short8*)((const char*)Bl + byt);
      }
      #pragma unroll
      for(int m = 0; m < 4; ++m)
        #pragma unroll
        for(int n = 0; n < 4; ++n)
          acc[m][n] = mfma16(af[m], bfr[n], acc[m][n]);
    }
  }

  // ---------- epilogue: LDS-staged, vectorized 16B stores ----------
  __syncthreads();                       // all ds_reads done before LDS reuse
  if constexpr(EPI == 4){
    float* fs = (float*)smem8;           // [64][128] fp32, two passes
    #pragma unroll
    for(int h = 0; h < 2; ++h){
      if(wm == h){
        #pragma unroll
        for(int m = 0; m < 4; ++m)
          #pragma unroll
          for(int n = 0; n < 4; ++n){
            int cc = wn * 64 + n * 16 + lr;
            int c = colBase + cc;
            #pragma unroll
            for(int j = 0; j < 4; ++j){
              int r2 = m * 16 + lk * 4 + j;
              int r = rowBase + h * 64 + r2;
              fs[r2 * 128 + cc] = acc[m][n][j]
                + h2f(accvH[(size_t)r * 256 + c]) + h2f(skipH[(size_t)r * 256 + c]);
            }
          }
      }
      __syncthreads();
      for(int ch = tid; ch < 2048; ch += 256){
        int rr = ch >> 5, cc = (ch & 31) << 2;
        int r = rowBase + h * 64 + rr;
        if(r < Mreal)
          *(float4*)&((float*)Out)[(size_t)r * Nld + colBase + cc] = *(float4*)&fs[rr * 128 + cc];
      }
      __syncthreads();
    }
  } else if constexpr(EPI == 0){
    int sec = by >> 1;                   // 0 q | 1 skip | 2 qWe | 3 k | 4 v
    u16* us = (u16*)smem8;               // [128][128] u16 (bf16 or fp16)
    #pragma unroll
    for(int m = 0; m < 4; ++m)
      #pragma unroll
      for(int n = 0; n < 4; ++n){
        int cc = wn * 64 + n * 16 + lr;
        #pragma unroll
        for(int j = 0; j < 4; ++j){
          int rr = wm * 64 + m * 16 + lk * 4 + j;
          float v = acc[m][n][j] + bias[colBase + cc];
          us[rr * 128 + cc] = (sec == 1) ? f2h(v) : f2bf(v);
        }
      }
    __syncthreads();
    u16* dstp; int cofs, ldd;
    if(sec == 0){ dstp = (u16*)Out; cofs = colBase; ldd = 512; }
    else if(sec == 1){ dstp = skipOut; cofs = colBase - 256; ldd = 256; }
    else if(sec == 2){ dstp = (u16*)Out; cofs = colBase - 256; ldd = 512; }
    else { dstp = kvout; cofs = colBase - 768; ldd = 512; }
    for(int ch = tid; ch < 2048; ch += 256){
      int rr = ch >> 4, cc = (ch & 15) << 3;
      int r = rowBase + rr;
      if(r < Mreal)
        *(short8*)&dstp[(size_t)r * ldd + cofs + cc] = *(short8*)&us[rr * 128 + cc];
    }
  } else {
    // bf16 single-pass: EPI 1 (bias+relu), 3 (accv+skip+relu), 5 (plain)
    u16* us = (u16*)smem8;               // [128][128] bf16
    #pragma unroll
    for(int m = 0; m < 4; ++m)
      #pragma unroll
      for(int n = 0; n < 4; ++n){
        int cc = wn * 64 + n * 16 + lr;
        int c = colBase + cc;
        #pragma unroll
        for(int j = 0; j < 4; ++j){
          int rr = wm * 64 + m * 16 + lk * 4 + j;
          float v = acc[m][n][j];
          if constexpr(EPI == 1){ v += bias[c]; v = fmaxf(v, 0.f); }
          else if constexpr(EPI == 3){
            int r = rowBase + rr;
            v += h2f(accvH[(size_t)r * 256 + c]) + h2f(skipH[(size_t)r * 256 + c]);
            v = fmaxf(v, 0.f);
          }
          us[rr * 128 + cc] = f2bf(v);
        }
      }
    __syncthreads();
    for(int ch = tid; ch < 2048; ch += 256){
      int rr = ch >> 4, cc = (ch & 15) << 3;
      int r = rowBase + rr;
      if(r < Mreal)
        *(short8*)&((u16*)Out)[(size_t)r * Nld + colBase + cc] = *(short8*)&us[rr * 128 + cc];
    }
  }
}

// ---------------- GEMM kernel wrappers ----------------
__global__ __launch_bounds__(256) void slab_k(
    const u16* __restrict__ A, const u16* __restrict__ Bt,
    const float* __restrict__ bias, u16* __restrict__ qq,
    u16* __restrict__ kvout, u16* __restrict__ skipOut){
  __shared__ short8 smem[2048];
  gemm_body<64,0,0>(smem, A, Bt, bias, qq, nullptr, nullptr, nullptr, kvout, skipOut,
                    blockIdx.x, blockIdx.y, 0, NN, 512, 256, 0, 0, 0);
}

__global__ __launch_bounds__(256) void out3_k(
    const u16* __restrict__ A, const u16* __restrict__ Bt, u16* __restrict__ Out,
    const u16* __restrict__ accvH, const u16* __restrict__ skipH){
  __shared__ short8 smem[2048];
  gemm_body<64,3,0>(smem, A, Bt, nullptr, Out, accvH, skipH, nullptr, nullptr, nullptr,
                    blockIdx.x, blockIdx.y, 0, NN, 256, 256, 0, 0, 0);
}

__global__ __launch_bounds__(256) void out4_k(
    const u16* __restrict__ A, const u16* __restrict__ Bt, float* __restrict__ Out,
    const u16* __restrict__ accvH, const u16* __restrict__ skipH){
  __shared__ short8 smem[2048];
  gemm_body<64,4,0>(smem, A, Bt, nullptr, Out, accvH, skipH, nullptr, nullptr, nullptr,
                    blockIdx.x, blockIdx.y, 0, NN, 256, 256, 0, 0, 0);
}

// node-enc (158 blocks) + edge-enc (2502) + weight GEMMs (12) in one launch
__global__ __launch_bounds__(256) void enc_all_k(
    const u16* __restrict__ xbf, const u16* __restrict__ Wnet,
    const float* __restrict__ bne, u16* __restrict__ hbf,
    const u16* __restrict__ eabf, const u16* __restrict__ Weet,
    const float* __restrict__ bee, u16* __restrict__ efp, const int* __restrict__ eidp,
    const u16* __restrict__ WeBF, const u16* __restrict__ WqBF, u16* __restrict__ WcatQ){
  __shared__ short8 smem[2048];
  int b = blockIdx.x;
  if(b < 158){
    gemm_body<64,1,0>(smem, xbf, Wnet, bne, hbf, nullptr, nullptr, nullptr, nullptr, nullptr,
                      b >> 1, b & 1, 0, NN, 256, 128, 0, 0, 0);
  } else if(b < 2660){
    int bb = b - 158;
    gemm_body<32,1,1>(smem, eabf, Weet, bee, efp, nullptr, nullptr, eidp, nullptr, nullptr,
                      bb >> 1, bb & 1, 0, EE, 256, 32, 0, 0, 0);
  } else {
    int bb = b - 2660;   // 12 blocks: bx = bb&1, by = (bb>>1)&1, bz = bb>>2
    gemm_body<64,5,0>(smem, WeBF, WqBF, nullptr, WcatQ, nullptr, nullptr, nullptr, nullptr, nullptr,
                      bb & 1, (bb >> 1) & 1, bb >> 2, 256, 256, 256,
                      (size_t)256 * 256, (size_t)256 * 256, (size_t)1280 * 256 * 2);
  }
}

// ---------------- fused per-node attention pass ----------------
// qq row (ld 512 bf16): q[0:256) qWe[256:512)
// kvbf row (ld 512 bf16): k[0:256) v[256:512)
// efp row (ld 256 bf16): edge features in CSR slot order
// ONE node per WAVE; 4 groups of 16 lanes INTERLEAVED over the edge list
// (group eg handles p = p0+eg, +4, +8, ... — balanced for any degree);
// 2-edge unroll, direct srcp loads (R5-proven structure, 41.7 us).
__global__ __launch_bounds__(256) void node_pass_k(
    const u16* __restrict__ qq, const u16* __restrict__ efp,
    const u16* __restrict__ kvbf,
    const int* __restrict__ srcp, const int* __restrict__ offs,
    u16* __restrict__ accvH, u16* __restrict__ aggef)
{
  int wave = threadIdx.x >> 6, lane = threadIdx.x & 63;
  int n = blockIdx.x * 4 + wave;
  if(n >= NN) return;
  int li = lane & 15, eg = lane >> 4;
  const u16* qrow = qq + (size_t)n * 512 + li * 16;
  short8 qh0 = *(const short8*)(qrow),       qh1 = *(const short8*)(qrow + 8);
  short8 eh0 = *(const short8*)(qrow + 256), eh1 = *(const short8*)(qrow + 264);
  float q[16], e[16];
  #pragma unroll
  for(int d = 0; d < 8; ++d){
    q[d] = bf2f((u16)qh0[d]); q[8 + d] = bf2f((u16)qh1[d]);
    e[d] = bf2f((u16)eh0[d]); e[8 + d] = bf2f((u16)eh1[d]);
  }
  float av[16], ag[16];
  #pragma unroll
  for(int d = 0; d < 16; ++d){ av[d] = 0.f; ag[d] = 0.f; }
  float den = 0.f;
  int p0 = offs[n], pe = offs[n + 1];
  int p = p0 + eg;
  for(; p + 4 < pe; p += 8){
    int s1 = srcp[p], s2 = srcp[p + 4];
    const u16* kv1 = kvbf + ((size_t)s1 << 9) + li * 16;
    const u16* kv2 = kvbf + ((size_t)s2 << 9) + li * 16;
    const u16* e1 = efp + (((size_t)p) << 8) + li * 16;
    const u16* e2 = efp + (((size_t)(p + 4)) << 8) + li * 16;
    short8 kA1 = *(const short8*)(kv1),       kB1 = *(const short8*)(kv1 + 8);
    short8 vA1 = *(const short8*)(kv1 + 256), vB1 = *(const short8*)(kv1 + 264);
    short8 fA1 = *(const short8*)(e1),        fB1 = *(const short8*)(e1 + 8);
    short8 kA2 = *(const short8*)(kv2),       kB2 = *(const short8*)(kv2 + 8);
    short8 vA2 = *(const short8*)(kv2 + 256), vB2 = *(const short8*)(kv2 + 264);
    short8 fA2 = *(const short8*)(e2),        fB2 = *(const short8*)(e2 + 8);
    float sc1 = 0.f, sc2 = 0.f;
    #pragma unroll
    for(int d = 0; d < 8; ++d){
      sc1 += q[d]   * bf2f((u16)kA1[d]) + e[d]   * bf2f((u16)fA1[d]);
      sc1 += q[8+d] * bf2f((u16)kB1[d]) + e[8+d] * bf2f((u16)fB1[d]);
      sc2 += q[d]   * bf2f((u16)kA2[d]) + e[d]   * bf2f((u16)fA2[d]);
      sc2 += q[8+d] * bf2f((u16)kB2[d]) + e[8+d] * bf2f((u16)fB2[d]);
    }
    sc1 += __shfl_xor(sc1, 1); sc2 += __shfl_xor(sc2, 1);
    sc1 += __shfl_xor(sc1, 2); sc2 += __shfl_xor(sc2, 2);
    sc1 += __shfl_xor(sc1, 4); sc2 += __shfl_xor(sc2, 4);
    sc1 += __shfl_xor(sc1, 8); sc2 += __shfl_xor(sc2, 8);
    float w1 = __expf(sc1 * 0.0625f);
    float w2 = __expf(sc2 * 0.0625f);
    den += w1 + w2;
    #pragma unroll
    for(int d = 0; d < 8; ++d){
      av[d]   += w1 * bf2f((u16)vA1[d]) + w2 * bf2f((u16)vA2[d]);
      av[8+d] += w1 * bf2f((u16)vB1[d]) + w2 * bf2f((u16)vB2[d]);
      ag[d]   += w1 * bf2f((u16)fA1[d]) + w2 * bf2f((u16)fA2[d]);
      ag[8+d] += w1 * bf2f((u16)fB1[d]) + w2 * bf2f((u16)fB2[d]);
    }
  }
  if(p < pe){
    int s = srcp[p];
    const u16* kvp = kvbf + ((size_t)s << 9) + li * 16;
    const u16* ep = efp + (((size_t)p) << 8) + li * 16;
    short8 kA = *(const short8*)(kvp),       kB = *(const short8*)(kvp + 8);
    short8 vA = *(const short8*)(kvp + 256), vB = *(const short8*)(kvp + 264);
    short8 fA = *(const short8*)(ep),        fB = *(const short8*)(ep + 8);
    float part = 0.f;
    #pragma unroll
    for(int d = 0; d < 8; ++d){
      part += q[d]   * bf2f((u16)kA[d]) + e[d]   * bf2f((u16)fA[d]);
      part += q[8+d] * bf2f((u16)kB[d]) + e[8+d] * bf2f((u16)fB[d]);
    }
    part += __shfl_xor(part, 1);
    part += __shfl_xor(part, 2);
    part += __shfl_xor(part, 4);
    part += __shfl_xor(part, 8);
    float wgt = __expf(part * 0.0625f);
    den += wgt;
    #pragma unroll
    for(int d = 0; d < 8; ++d){
      av[d]   += wgt * bf2f((u16)vA[d]);
      av[8+d] += wgt * bf2f((u16)vB[d]);
      ag[d]   += wgt * bf2f((u16)fA[d]);
      ag[8+d] += wgt * bf2f((u16)fB[d]);
    }
  }
  // combine the 4 edge-groups (convergent — all 64 lanes active here)
  #pragma unroll
  for(int d = 0; d < 16; ++d){
    av[d] += __shfl_xor(av[d], 16); av[d] += __shfl_xor(av[d], 32);
    ag[d] += __shfl_xor(ag[d], 16); ag[d] += __shfl_xor(ag[d], 32);
  }
  den += __shfl_xor(den, 16); den += __shfl_xor(den, 32);
  float rden = 1.f / fmaxf(den, 1e-16f);          // pre-divide (linear in We)
  if(eg == 0){
    u16* ao = accvH + (size_t)n * 256 + li * 16;
    #pragma unroll
    for(int t = 0; t < 2; ++t){
      short8 o;
      #pragma unroll
      for(int d = 0; d < 8; ++d) o[d] = (short)f2h(av[t*8+d] * rden);
      *(short8*)(ao + t * 8) = o;
    }
  } else if(eg == 1){
    u16* go = aggef + (size_t)n * 256 + li * 16;
    #pragma unroll
    for(int t = 0; t < 2; ++t){
      short8 o;
      #pragma unroll
      for(int d = 0; d < 8; ++d) o[d] = (short)f2bf(ag[t*8+d] * rden);
      *(short8*)(go + t * 8) = o;
    }
  }
}

// ---------------- launch ----------------
extern "C" void kernel_launch(void* const* d_in, const int* in_sizes, int n_in,
                              void* d_out, int out_size, void* d_ws, size_t ws_size,
                              hipStream_t stream){
  const float* x     = (const float*)d_in[0];
  const float* eattr = (const float*)d_in[1];
  const int*   src   = (const int*)d_in[2];
  const int*   dst   = (const int*)d_in[3];
  const float* Wee   = (const float*)d_in[4];
  const float* bee   = (const float*)d_in[5];
  const float* Wne   = (const float*)d_in[6];
  const float* bne   = (const float*)d_in[7];
  WPack P;
  for(int l = 0; l < 3; ++l){
    const int b = 8 + l * 9;
    P.Wq[l] = (const float*)d_in[b + 0]; P.bq[l] = (const float*)d_in[b + 1];
    P.Wk[l] = (const float*)d_in[b + 2]; P.bk[l] = (const float*)d_in[b + 3];
    P.Wv[l] = (const float*)d_in[b + 4]; P.bv[l] = (const float*)d_in[b + 5];
    P.We[l] = (const float*)d_in[b + 6];
    P.Ws[l] = (const float*)d_in[b + 7]; P.bs[l] = (const float*)d_in[b + 8];
  }

  char* w = (char*)d_ws; size_t off = 0;
  auto alloc = [&](size_t bytes)->char*{
    char* p = w + off; off = (off + bytes + 255) & ~(size_t)255; return p;
  };
  u16*   Wcat  = (u16*)  alloc((size_t)3 * 1280 * 256 * 2);
  u16*   Wet   = (u16*)  alloc((size_t)3 * 256 * 256 * 2);
  u16*   WqBF  = (u16*)  alloc((size_t)3 * 256 * 256 * 2);
  u16*   WeBF  = (u16*)  alloc((size_t)3 * 256 * 256 * 2);
  float* biasc = (float*)alloc((size_t)3 * 1280 * 4);
  u16*   Wnet  = (u16*)  alloc((size_t)256 * 128 * 2);
  u16*   Weet  = (u16*)  alloc((size_t)256 * 32 * 2);
  u16*   xbf   = (u16*)  alloc((size_t)MPN * 128 * 2);
  u16*   eabf  = (u16*)  alloc((size_t)MPE * 32 * 2);
  u16*   hbf   = (u16*)  alloc((size_t)MPN * 256 * 2);
  u16*   qq    = (u16*)  alloc((size_t)MPN * 512 * 2);
  u16*   skipf = (u16*)  alloc((size_t)MPN * 256 * 2);
  u16*   kvbf  = (u16*)  alloc((size_t)MPN * 512 * 2);
  u16*   efp   = (u16*)  alloc((size_t)MPE * 256 * 2);
  int*   cnt   = (int*)  alloc((size_t)NN * 4);
  int*   offs  = (int*)  alloc((size_t)(NN + 1) * 4);
  int*   cursor= (int*)  alloc((size_t)NN * 4);
  int*   eids  = (int*)  alloc((size_t)EE * 4);
  int*   eidp  = (int*)  alloc((size_t)MPE * 4);
  int*   srcp  = (int*)  alloc((size_t)EE * 4);
  u16*   accv  = (u16*)  alloc((size_t)MPN * 256 * 2);
  u16*   aggef = (u16*)  alloc((size_t)MPN * 256 * 2);
  if(off > ws_size) return;   // workspace too small -> visible validation failure

  // CSR build (deterministic: rank-by-edge-id, no sort)
  hipMemsetAsync(cnt, 0, (size_t)NN * 4, stream);
  count_k <<<(EE + 255) / 256, 256, 0, stream>>>(dst, cnt);
  scan_k  <<<1, 1024, 0, stream>>>(cnt, offs, cursor);
  scatter_k<<<(EE + 255) / 256, 256, 0, stream>>>(dst, cursor, eids);
  rank_k  <<<(MPE + 255) / 256, 256, 0, stream>>>(dst, src, offs, eids, eidp, srcp);

  // all input/weight conversion in one launch
  prep_all_k<<<PG5, 256, 0, stream>>>(x, eattr, P, Wne, Wee,
      xbf, eabf, Wcat, Wet, WqBF, WeBF, biasc, Wnet, Weet);

  // node encoder + edge encoder + qWe weight GEMMs in one launch
  enc_all_k<<<2672, 256, 0, stream>>>(
      xbf, Wnet, bne, hbf,
      eabf, Weet, bee, efp, eidp,
      WeBF, WqBF, Wcat + (size_t)512 * 256);

  for(int l = 0; l < 3; ++l){
    // fused q|skip|qWe|k|v slab -> qq bf16 + skipf fp16 + kv bf16
    slab_k<<<dim3(MPN / 128, 10), 256, 0, stream>>>(
        hbf, Wcat + (size_t)l * 1280 * 256, biasc + (size_t)l * 1280, qq, kvbf, skipf);
    // per-node attention: scores + exp + weighted sums (pre-divided by denom)
    node_pass_k<<<NN / 4, 256, 0, stream>>>(qq, efp, kvbf, srcp, offs, accv, aggef);
    // out = accv + aggef@We + skip  (+relu, bf16 for layers 0,1; fp32 out for layer 2)
    if(l < 2)
      out3_k<<<dim3(MPN / 128, 2), 256, 0, stream>>>(
          aggef, Wet + (size_t)l * 256 * 256, hbf, accv, skipf);
    else
      out4_k<<<dim3(MPN / 128, 2), 256, 0, stream>>>(
          aggef, Wet + (size_t)l * 256 * 256, (float*)d_out, accv, skipf);
  }
}

// Round 12
// 337.616 us; speedup vs baseline: 1.2264x; 1.0028x over previous
//
#include <hip/hip_runtime.h>
#include <cstdint>

typedef unsigned short u16;
typedef __attribute__((ext_vector_type(8))) short short8;
typedef __attribute__((ext_vector_type(8))) __bf16 bf16x8;
typedef __attribute__((ext_vector_type(4))) float f32x4;

#define DEV __device__ __forceinline__

DEV u16 f2bf(float f){
  uint32_t u = __float_as_uint(f);
  u += 0x7fffu + ((u >> 16) & 1u);
  return (u16)(u >> 16);
}
DEV float bf2f(u16 h){ return __uint_as_float(((uint32_t)h) << 16); }
DEV u16 f2h(float f){ return __builtin_bit_cast(u16, (_Float16)f); }
DEV float h2f(u16 h){ return (float)__builtin_bit_cast(_Float16, h); }

DEV f32x4 mfma16(short8 a, short8 b, f32x4 c){
  return __builtin_amdgcn_mfma_f32_16x16x32_bf16(
      __builtin_bit_cast(bf16x8, a), __builtin_bit_cast(bf16x8, b), c, 0, 0, 0);
}

#define NN 10000
#define EE 160000
#define MPN 10112   /* 79*128  */
#define MPE 160128  /* 1251*128 */

// ---------------- CSR scan (count fused into prep_all) ----------------
// single-block scan of the 10000 counts (reads only 40KB -> cheap on one CU)
__global__ __launch_bounds__(1024) void scan_k(const int* __restrict__ cnt,
                                               int* __restrict__ offs,
                                               int* __restrict__ cursor){
  __shared__ int psum[1024];
  int tid = threadIdx.x;
  int base = tid * 10;
  int loc[10];
  int s = 0;
  #pragma unroll
  for(int j = 0; j < 10; ++j){
    int idx = base + j;
    int v = (idx < NN) ? cnt[idx] : 0;
    loc[j] = s; s += v;
  }
  psum[tid] = s;
  __syncthreads();
  for(int d = 1; d < 1024; d <<= 1){
    int t = (tid >= d) ? psum[tid - d] : 0;
    __syncthreads();
    psum[tid] += t;
    __syncthreads();
  }
  int add = (tid > 0) ? psum[tid - 1] : 0;
  #pragma unroll
  for(int j = 0; j < 10; ++j){
    int idx = base + j;
    if(idx < NN){ int v = loc[j] + add; offs[idx] = v; cursor[idx] = v; }
  }
  if(tid == 0) offs[NN] = EE;
}

__global__ void scatter_k(const int* __restrict__ dst, int* __restrict__ cursor,
                          int* __restrict__ eids){
  int i = blockIdx.x * 256 + threadIdx.x;
  if(i < EE){ int p = atomicAdd(&cursor[dst[i]], 1); eids[p] = i; }
}

// deterministic rank: slot(e) = offs[dst] + #{e' in bucket : e' < e}
__global__ void rank_k(const int* __restrict__ dst, const int* __restrict__ src,
                       const int* __restrict__ offs, const int* __restrict__ eids,
                       int* __restrict__ eidp, int* __restrict__ srcp){
  int e = blockIdx.x * 256 + threadIdx.x;
  if(e >= MPE) return;
  if(e >= EE){ eidp[e] = e; return; }      // pad slots -> zero rows of eabf
  int n = dst[e];
  int p0 = offs[n], p1 = offs[n + 1];
  int rk = 0;
  for(int p = p0; p < p1; ++p) rk += (eids[p] < e) ? 1 : 0;
  int slot = p0 + rk;
  eidp[slot] = e;
  srcp[slot] = src[e];
}

// ---------------- weight / input prep + dst-count (single fused kernel) ----------------
struct WPack {
  const float* Wq[3]; const float* Wk[3]; const float* Wv[3];
  const float* Ws[3]; const float* We[3];
  const float* bq[3]; const float* bk[3]; const float* bv[3]; const float* bs[3];
};

#define PG0 5056                 /* xbf   : MPN*128/256 */
#define PG1 (PG0 + 20016)        /* eabf  : MPE*32/256  */
#define PG2 (PG1 + 3840)         /* Wcat/Wet : 3*1280   */
#define PG3 (PG2 + 1536)         /* WqBF/WeBF: 3*512    */
#define PG4 (PG3 + 15)           /* biasc */
#define PG5 (PG4 + 256)          /* encoders */
#define PG6 (PG5 + 625)          /* dst count: EE/256 */

// Wcat rows per layer: [0,256) Wq^T | [256,512) Ws^T | [512,768) qWe (GEMM EPI5)
//                      | [768,1024) Wk^T | [1024,1280) Wv^T
__global__ __launch_bounds__(256) void prep_all_k(
    const float* __restrict__ x, const float* __restrict__ eattr, WPack P,
    const float* __restrict__ Wne, const float* __restrict__ Wee,
    const int* __restrict__ dst, int* __restrict__ cnt,
    u16* __restrict__ xbf, u16* __restrict__ eabf,
    u16* __restrict__ Wcat, u16* __restrict__ Wet,
    u16* __restrict__ WqBF, u16* __restrict__ WeBF,
    float* __restrict__ biasc, u16* __restrict__ Wnet, u16* __restrict__ Weet)
{
  int b = blockIdx.x, tid = threadIdx.x;
  if(b < PG0){
    int i = b * 256 + tid;
    xbf[i] = (i < NN * 128) ? f2bf(x[i]) : (u16)0;
  } else if(b < PG1){
    int i = (b - PG0) * 256 + tid;
    eabf[i] = (i < EE * 32) ? f2bf(eattr[i]) : (u16)0;
  } else if(b < PG2){
    int b2 = b - PG1; int l = b2 / 1280, r = b2 % 1280; int k = tid;
    float v;
    if(r < 256)       v = P.Wq[l][k * 256 + r];
    else if(r < 512)  v = P.Ws[l][k * 256 + (r - 256)];
    else if(r < 768){ Wet[((size_t)l * 256 + (r - 512)) * 256 + k] =
                        f2bf(P.We[l][k * 256 + (r - 512)]); return; }
    else if(r < 1024) v = P.Wk[l][k * 256 + (r - 768)];
    else              v = P.Wv[l][k * 256 + (r - 1024)];
    Wcat[((size_t)l * 1280 + r) * 256 + k] = f2bf(v);
  } else if(b < PG3){
    int b3 = b - PG2; int l = b3 >> 9, rr = b3 & 511; int t = tid;
    if(rr < 256) WqBF[((size_t)l * 256 + rr) * 256 + t] = f2bf(P.Wq[l][rr * 256 + t]);
    else         WeBF[((size_t)l * 256 + (rr - 256)) * 256 + t] = f2bf(P.We[l][(rr - 256) * 256 + t]);
  } else if(b < PG4){
    int b4 = b - PG3; int l = b4 / 5, seg = b4 % 5; int t = tid;
    float v;
    if(seg == 0)      v = P.bq[l][t];
    else if(seg == 1) v = P.bs[l][t];
    else if(seg == 2){
      const float* we = P.We[l] + (size_t)t * 256; const float* bq = P.bq[l];
      float s = 0.f;
      for(int c = 0; c < 256; ++c) s += bq[c] * we[c];
      v = s;
    }
    else if(seg == 3) v = P.bk[l][t];
    else              v = P.bv[l][t];
    biasc[(size_t)l * 1280 + seg * 256 + t] = v;
  } else if(b < PG5){
    int n = b - PG4;
    if(tid < 128) Wnet[n * 128 + tid] = f2bf(Wne[(size_t)tid * 256 + n]);
    if(tid < 32)  Weet[n * 32 + tid]  = f2bf(Wee[(size_t)tid * 256 + n]);
  } else {
    int i = (b - PG5) * 256 + tid;
    if(i < EE) atomicAdd(&cnt[dst[i]], 1);
  }
}

// ---------------- MFMA GEMM body:  C[M,N] = A[M,K](bf16) @ Bt[N,K]^T(bf16) ----------------
// AG: gather A rows through rowmap.
// EPI 0: +bias; sec(by/2): 0 q->Out(ld512) | 1 skip->skipOut fp16(ld256)
//        | 2 qWe->Out(+256) | 3 k->kvout | 4 v->kvout(+256)
// EPI 1: +bias, relu -> bf16 (Out, ld Nld)
// EPI 3: acc + accv(fp16) + skip(fp16), relu -> bf16
// EPI 4: acc + accv(fp16) + skip(fp16) -> fp32
// EPI 5: plain -> bf16 (weight-prep GEMM; batched over bz)
template<int BK, int EPI, int AG>
DEV void gemm_body(short8* smem8,
    const u16* __restrict__ A, const u16* __restrict__ Bt,
    const float* __restrict__ bias, void* Out,
    const u16* __restrict__ accvH, const u16* __restrict__ skipH,
    const int* __restrict__ rowmap, u16* __restrict__ kvout,
    u16* __restrict__ skipOut,
    int bx, int by, int bz,
    int Mreal, int Nld, int K, size_t sA, size_t sB, size_t sOb)
{
  constexpr int CPR = BK / 8;           // 16B chunks per LDS row
  constexpr int SW  = (BK == 64) ? 7 : 3;
  u16* Al = (u16*)smem8;
  u16* Bl = Al + 128 * BK;
  A  += (size_t)bz * sA;
  Bt += (size_t)bz * sB;
  Out = (void*)((char*)Out + (size_t)bz * sOb);
  int tid = threadIdx.x, lane = tid & 63;
  int rowBase = bx * 128, colBase = by * 128;
  int wave = tid >> 6, wm = wave >> 1, wn = wave & 1;
  int lr = lane & 15, lk = lane >> 4;
  f32x4 acc[4][4] = {};
  int nkt = K / BK;
  for(int kt = 0; kt < nkt; ++kt){
    __syncthreads();
    for(int ci = tid; ci < 128 * CPR; ci += 256){
      int r = ci / CPR, cb = ci % CPR;
      int ar = AG ? rowmap[rowBase + r] : (rowBase + r);
      int d = (r * CPR + (cb ^ (r & SW))) * 8;     // swizzled dest (u16 units)
      *(short8*)&Al[d] = *(const short8*)&A [(size_t)ar * K + kt * BK + cb * 8];
      *(short8*)&Bl[d] = *(const short8*)&Bt[(size_t)(colBase + r) * K + kt * BK + cb * 8];
    }
    __syncthreads();
    #pragma unroll
    for(int kk = 0; kk < BK / 32; ++kk){
      short8 af[4], bfr[4];
      #pragma unroll
      for(int m = 0; m < 4; ++m){
        int r = wm * 64 + m * 16 + lr;
        int byt = r * (BK * 2) + kk * 64 + lk * 16; byt ^= (r & SW) << 4;
        af[m] = *(const short8*)((const char*)Al + byt);
      }
      #pragma unroll
      for(int n = 0; n < 4; ++n){
        int r = wn * 64 + n * 16 + lr;
        int byt = r * (BK * 2) + kk * 64 + lk * 16; byt ^= (r & SW) << 4;
        bfr[n] = *(const short8*)((const char*)Bl + byt);
      }
      #pragma unroll
      for(int m = 0; m < 4; ++m)
        #pragma unroll
        for(int n = 0; n < 4; ++n)
          acc[m][n] = mfma16(af[m], bfr[n], acc[m][n]);
    }
  }

  // ---------- epilogue: LDS-staged, vectorized 16B stores ----------
  __syncthreads();                       // all ds_reads done before LDS reuse
  if constexpr(EPI == 4){
    float* fs = (float*)smem8;           // [64][128] fp32, two passes
    #pragma unroll
    for(int h = 0; h < 2; ++h){
      if(wm == h){
        #pragma unroll
        for(int m = 0; m < 4; ++m)
          #pragma unroll
          for(int n = 0; n < 4; ++n){
            int cc = wn * 64 + n * 16 + lr;
            int c = colBase + cc;
            #pragma unroll
            for(int j = 0; j < 4; ++j){
              int r2 = m * 16 + lk * 4 + j;
              int r = rowBase + h * 64 + r2;
              fs[r2 * 128 + cc] = acc[m][n][j]
                + h2f(accvH[(size_t)r * 256 + c]) + h2f(skipH[(size_t)r * 256 + c]);
            }
          }
      }
      __syncthreads();
      for(int ch = tid; ch < 2048; ch += 256){
        int rr = ch >> 5, cc = (ch & 31) << 2;
        int r = rowBase + h * 64 + rr;
        if(r < Mreal)
          *(float4*)&((float*)Out)[(size_t)r * Nld + colBase + cc] = *(float4*)&fs[rr * 128 + cc];
      }
      __syncthreads();
    }
  } else if constexpr(EPI == 0){
    int sec = by >> 1;                   // 0 q | 1 skip | 2 qWe | 3 k | 4 v
    u16* us = (u16*)smem8;               // [128][128] u16 (bf16 or fp16)
    #pragma unroll
    for(int m = 0; m < 4; ++m)
      #pragma unroll
      for(int n = 0; n < 4; ++n){
        int cc = wn * 64 + n * 16 + lr;
        #pragma unroll
        for(int j = 0; j < 4; ++j){
          int rr = wm * 64 + m * 16 + lk * 4 + j;
          float v = acc[m][n][j] + bias[colBase + cc];
          us[rr * 128 + cc] = (sec == 1) ? f2h(v) : f2bf(v);
        }
      }
    __syncthreads();
    u16* dstp; int cofs, ldd;
    if(sec == 0){ dstp = (u16*)Out; cofs = colBase; ldd = 512; }
    else if(sec == 1){ dstp = skipOut; cofs = colBase - 256; ldd = 256; }
    else if(sec == 2){ dstp = (u16*)Out; cofs = colBase - 256; ldd = 512; }
    else { dstp = kvout; cofs = colBase - 768; ldd = 512; }
    for(int ch = tid; ch < 2048; ch += 256){
      int rr = ch >> 4, cc = (ch & 15) << 3;
      int r = rowBase + rr;
      if(r < Mreal)
        *(short8*)&dstp[(size_t)r * ldd + cofs + cc] = *(short8*)&us[rr * 128 + cc];
    }
  } else {
    // bf16 single-pass: EPI 1 (bias+relu), 3 (accv+skip+relu), 5 (plain)
    u16* us = (u16*)smem8;               // [128][128] bf16
    #pragma unroll
    for(int m = 0; m < 4; ++m)
      #pragma unroll
      for(int n = 0; n < 4; ++n){
        int cc = wn * 64 + n * 16 + lr;
        int c = colBase + cc;
        #pragma unroll
        for(int j = 0; j < 4; ++j){
          int rr = wm * 64 + m * 16 + lk * 4 + j;
          float v = acc[m][n][j];
          if constexpr(EPI == 1){ v += bias[c]; v = fmaxf(v, 0.f); }
          else if constexpr(EPI == 3){
            int r = rowBase + rr;
            v += h2f(accvH[(size_t)r * 256 + c]) + h2f(skipH[(size_t)r * 256 + c]);
            v = fmaxf(v, 0.f);
          }
          us[rr * 128 + cc] = f2bf(v);
        }
      }
    __syncthreads();
    for(int ch = tid; ch < 2048; ch += 256){
      int rr = ch >> 4, cc = (ch & 15) << 3;
      int r = rowBase + rr;
      if(r < Mreal)
        *(short8*)&((u16*)Out)[(size_t)r * Nld + colBase + cc] = *(short8*)&us[rr * 128 + cc];
    }
  }
}

// ---------------- GEMM kernel wrappers ----------------
__global__ __launch_bounds__(256) void slab_k(
    const u16* __restrict__ A, const u16* __restrict__ Bt,
    const float* __restrict__ bias, u16* __restrict__ qq,
    u16* __restrict__ kvout, u16* __restrict__ skipOut){
  __shared__ short8 smem[2048];
  gemm_body<64,0,0>(smem, A, Bt, bias, qq, nullptr, nullptr, nullptr, kvout, skipOut,
                    blockIdx.x, blockIdx.y, 0, NN, 512, 256, 0, 0, 0);
}

__global__ __launch_bounds__(256) void out3_k(
    const u16* __restrict__ A, const u16* __restrict__ Bt, u16* __restrict__ Out,
    const u16* __restrict__ accvH, const u16* __restrict__ skipH){
  __shared__ short8 smem[2048];
  gemm_body<64,3,0>(smem, A, Bt, nullptr, Out, accvH, skipH, nullptr, nullptr, nullptr,
                    blockIdx.x, blockIdx.y, 0, NN, 256, 256, 0, 0, 0);
}

__global__ __launch_bounds__(256) void out4_k(
    const u16* __restrict__ A, const u16* __restrict__ Bt, float* __restrict__ Out,
    const u16* __restrict__ accvH, const u16* __restrict__ skipH){
  __shared__ short8 smem[2048];
  gemm_body<64,4,0>(smem, A, Bt, nullptr, Out, accvH, skipH, nullptr, nullptr, nullptr,
                    blockIdx.x, blockIdx.y, 0, NN, 256, 256, 0, 0, 0);
}

// node-enc (158 blocks) + edge-enc (2502) + weight GEMMs (12) in one launch
__global__ __launch_bounds__(256) void enc_all_k(
    const u16* __restrict__ xbf, const u16* __restrict__ Wnet,
    const float* __restrict__ bne, u16* __restrict__ hbf,
    const u16* __restrict__ eabf, const u16* __restrict__ Weet,
    const float* __restrict__ bee, u16* __restrict__ efp, const int* __restrict__ eidp,
    const u16* __restrict__ WeBF, const u16* __restrict__ WqBF, u16* __restrict__ WcatQ){
  __shared__ short8 smem[2048];
  int b = blockIdx.x;
  if(b < 158){
    gemm_body<64,1,0>(smem, xbf, Wnet, bne, hbf, nullptr, nullptr, nullptr, nullptr, nullptr,
                      b >> 1, b & 1, 0, NN, 256, 128, 0, 0, 0);
  } else if(b < 2660){
    int bb = b - 158;
    gemm_body<32,1,1>(smem, eabf, Weet, bee, efp, nullptr, nullptr, eidp, nullptr, nullptr,
                      bb >> 1, bb & 1, 0, EE, 256, 32, 0, 0, 0);
  } else {
    int bb = b - 2660;   // 12 blocks: bx = bb&1, by = (bb>>1)&1, bz = bb>>2
    gemm_body<64,5,0>(smem, WeBF, WqBF, nullptr, WcatQ, nullptr, nullptr, nullptr, nullptr, nullptr,
                      bb & 1, (bb >> 1) & 1, bb >> 2, 256, 256, 256,
                      (size_t)256 * 256, (size_t)256 * 256, (size_t)1280 * 256 * 2);
  }
}

// ---------------- fused per-node attention pass ----------------
// qq row (ld 512 bf16): q[0:256) qWe[256:512)
// kvbf row (ld 512 bf16): k[0:256) v[256:512)
// efp row (ld 256 bf16): edge features in CSR slot order (nontemporal reads —
// read-once stream; keep L2 for the kvbf gather table)
// ONE node per WAVE; 4 groups of 16 lanes INTERLEAVED over the edge list;
// 2-edge unroll with srcp SOFTWARE-PIPELINED one iteration ahead so the
// 12 data loads per iteration issue without a dependent srcp wait.
__global__ __launch_bounds__(256) void node_pass_k(
    const u16* __restrict__ qq, const u16* __restrict__ efp,
    const u16* __restrict__ kvbf,
    const int* __restrict__ srcp, const int* __restrict__ offs,
    u16* __restrict__ accvH, u16* __restrict__ aggef)
{
  int wave = threadIdx.x >> 6, lane = threadIdx.x & 63;
  int n = blockIdx.x * 4 + wave;
  if(n >= NN) return;
  int li = lane & 15, eg = lane >> 4;
  const u16* qrow = qq + (size_t)n * 512 + li * 16;
  short8 qh0 = *(const short8*)(qrow),       qh1 = *(const short8*)(qrow + 8);
  short8 eh0 = *(const short8*)(qrow + 256), eh1 = *(const short8*)(qrow + 264);
  float q[16], e[16];
  #pragma unroll
  for(int d = 0; d < 8; ++d){
    q[d] = bf2f((u16)qh0[d]); q[8 + d] = bf2f((u16)qh1[d]);
    e[d] = bf2f((u16)eh0[d]); e[8 + d] = bf2f((u16)eh1[d]);
  }
  float av[16], ag[16];
  #pragma unroll
  for(int d = 0; d < 16; ++d){ av[d] = 0.f; ag[d] = 0.f; }
  float den = 0.f;
  int p0 = offs[n], pe = offs[n + 1];
  int p = p0 + eg;
  int s1 = (p < pe) ? srcp[p] : 0;
  int s2 = (p + 4 < pe) ? srcp[p + 4] : 0;
  while(p + 4 < pe){
    int pn = p + 8;
    int sn1 = (pn < pe) ? srcp[pn] : 0;           // prefetch next iteration
    int sn2 = (pn + 4 < pe) ? srcp[pn + 4] : 0;
    const u16* kv1 = kvbf + ((size_t)s1 << 9) + li * 16;
    const u16* kv2 = kvbf + ((size_t)s2 << 9) + li * 16;
    const u16* e1 = efp + (((size_t)p) << 8) + li * 16;
    const u16* e2 = efp + (((size_t)(p + 4)) << 8) + li * 16;
    short8 kA1 = *(const short8*)(kv1),       kB1 = *(const short8*)(kv1 + 8);
    short8 vA1 = *(const short8*)(kv1 + 256), vB1 = *(const short8*)(kv1 + 264);
    short8 fA1 = __builtin_nontemporal_load((const short8*)e1);
    short8 fB1 = __builtin_nontemporal_load((const short8*)(e1 + 8));
    short8 kA2 = *(const short8*)(kv2),       kB2 = *(const short8*)(kv2 + 8);
    short8 vA2 = *(const short8*)(kv2 + 256), vB2 = *(const short8*)(kv2 + 264);
    short8 fA2 = __builtin_nontemporal_load((const short8*)e2);
    short8 fB2 = __builtin_nontemporal_load((const short8*)(e2 + 8));
    float sc1 = 0.f, sc2 = 0.f;
    #pragma unroll
    for(int d = 0; d < 8; ++d){
      sc1 += q[d]   * bf2f((u16)kA1[d]) + e[d]   * bf2f((u16)fA1[d]);
      sc1 += q[8+d] * bf2f((u16)kB1[d]) + e[8+d] * bf2f((u16)fB1[d]);
      sc2 += q[d]   * bf2f((u16)kA2[d]) + e[d]   * bf2f((u16)fA2[d]);
      sc2 += q[8+d] * bf2f((u16)kB2[d]) + e[8+d] * bf2f((u16)fB2[d]);
    }
    sc1 += __shfl_xor(sc1, 1); sc2 += __shfl_xor(sc2, 1);
    sc1 += __shfl_xor(sc1, 2); sc2 += __shfl_xor(sc2, 2);
    sc1 += __shfl_xor(sc1, 4); sc2 += __shfl_xor(sc2, 4);
    sc1 += __shfl_xor(sc1, 8); sc2 += __shfl_xor(sc2, 8);
    float w1 = __expf(sc1 * 0.0625f);
    float w2 = __expf(sc2 * 0.0625f);
    den += w1 + w2;
    #pragma unroll
    for(int d = 0; d < 8; ++d){
      av[d]   += w1 * bf2f((u16)vA1[d]) + w2 * bf2f((u16)vA2[d]);
      av[8+d] += w1 * bf2f((u16)vB1[d]) + w2 * bf2f((u16)vB2[d]);
      ag[d]   += w1 * bf2f((u16)fA1[d]) + w2 * bf2f((u16)fA2[d]);
      ag[8+d] += w1 * bf2f((u16)fB1[d]) + w2 * bf2f((u16)fB2[d]);
    }
    p = pn; s1 = sn1; s2 = sn2;
  }
  if(p < pe){
    const u16* kvp = kvbf + ((size_t)s1 << 9) + li * 16;
    const u16* ep = efp + (((size_t)p) << 8) + li * 16;
    short8 kA = *(const short8*)(kvp),       kB = *(const short8*)(kvp + 8);
    short8 vA = *(const short8*)(kvp + 256), vB = *(const short8*)(kvp + 264);
    short8 fA = __builtin_nontemporal_load((const short8*)ep);
    short8 fB = __builtin_nontemporal_load((const short8*)(ep + 8));
    float part = 0.f;
    #pragma unroll
    for(int d = 0; d < 8; ++d){
      part += q[d]   * bf2f((u16)kA[d]) + e[d]   * bf2f((u16)fA[d]);
      part += q[8+d] * bf2f((u16)kB[d]) + e[8+d] * bf2f((u16)fB[d]);
    }
    part += __shfl_xor(part, 1);
    part += __shfl_xor(part, 2);
    part += __shfl_xor(part, 4);
    part += __shfl_xor(part, 8);
    float wgt = __expf(part * 0.0625f);
    den += wgt;
    #pragma unroll
    for(int d = 0; d < 8; ++d){
      av[d]   += wgt * bf2f((u16)vA[d]);
      av[8+d] += wgt * bf2f((u16)vB[d]);
      ag[d]   += wgt * bf2f((u16)fA[d]);
      ag[8+d] += wgt * bf2f((u16)fB[d]);
    }
  }
  // combine the 4 edge-groups (convergent — all 64 lanes active here)
  #pragma unroll
  for(int d = 0; d < 16; ++d){
    av[d] += __shfl_xor(av[d], 16); av[d] += __shfl_xor(av[d], 32);
    ag[d] += __shfl_xor(ag[d], 16); ag[d] += __shfl_xor(ag[d], 32);
  }
  den += __shfl_xor(den, 16); den += __shfl_xor(den, 32);
  float rden = 1.f / fmaxf(den, 1e-16f);          // pre-divide (linear in We)
  if(eg == 0){
    u16* ao = accvH + (size_t)n * 256 + li * 16;
    #pragma unroll
    for(int t = 0; t < 2; ++t){
      short8 o;
      #pragma unroll
      for(int d = 0; d < 8; ++d) o[d] = (short)f2h(av[t*8+d] * rden);
      *(short8*)(ao + t * 8) = o;
    }
  } else if(eg == 1){
    u16* go = aggef + (size_t)n * 256 + li * 16;
    #pragma unroll
    for(int t = 0; t < 2; ++t){
      short8 o;
      #pragma unroll
      for(int d = 0; d < 8; ++d) o[d] = (short)f2bf(ag[t*8+d] * rden);
      *(short8*)(go + t * 8) = o;
    }
  }
}

// ---------------- launch ----------------
extern "C" void kernel_launch(void* const* d_in, const int* in_sizes, int n_in,
                              void* d_out, int out_size, void* d_ws, size_t ws_size,
                              hipStream_t stream){
  const float* x     = (const float*)d_in[0];
  const float* eattr = (const float*)d_in[1];
  const int*   src   = (const int*)d_in[2];
  const int*   dst   = (const int*)d_in[3];
  const float* Wee   = (const float*)d_in[4];
  const float* bee   = (const float*)d_in[5];
  const float* Wne   = (const float*)d_in[6];
  const float* bne   = (const float*)d_in[7];
  WPack P;
  for(int l = 0; l < 3; ++l){
    const int b = 8 + l * 9;
    P.Wq[l] = (const float*)d_in[b + 0]; P.bq[l] = (const float*)d_in[b + 1];
    P.Wk[l] = (const float*)d_in[b + 2]; P.bk[l] = (const float*)d_in[b + 3];
    P.Wv[l] = (const float*)d_in[b + 4]; P.bv[l] = (const float*)d_in[b + 5];
    P.We[l] = (const float*)d_in[b + 6];
    P.Ws[l] = (const float*)d_in[b + 7]; P.bs[l] = (const float*)d_in[b + 8];
  }

  char* w = (char*)d_ws; size_t off = 0;
  auto alloc = [&](size_t bytes)->char*{
    char* p = w + off; off = (off + bytes + 255) & ~(size_t)255; return p;
  };
  u16*   Wcat  = (u16*)  alloc((size_t)3 * 1280 * 256 * 2);
  u16*   Wet   = (u16*)  alloc((size_t)3 * 256 * 256 * 2);
  u16*   WqBF  = (u16*)  alloc((size_t)3 * 256 * 256 * 2);
  u16*   WeBF  = (u16*)  alloc((size_t)3 * 256 * 256 * 2);
  float* biasc = (float*)alloc((size_t)3 * 1280 * 4);
  u16*   Wnet  = (u16*)  alloc((size_t)256 * 128 * 2);
  u16*   Weet  = (u16*)  alloc((size_t)256 * 32 * 2);
  u16*   xbf   = (u16*)  alloc((size_t)MPN * 128 * 2);
  u16*   eabf  = (u16*)  alloc((size_t)MPE * 32 * 2);
  u16*   hbf   = (u16*)  alloc((size_t)MPN * 256 * 2);
  u16*   qq    = (u16*)  alloc((size_t)MPN * 512 * 2);
  u16*   skipf = (u16*)  alloc((size_t)MPN * 256 * 2);
  u16*   kvbf  = (u16*)  alloc((size_t)MPN * 512 * 2);
  u16*   efp   = (u16*)  alloc((size_t)MPE * 256 * 2);
  int*   cnt   = (int*)  alloc((size_t)NN * 4);
  int*   offs  = (int*)  alloc((size_t)(NN + 1) * 4);
  int*   cursor= (int*)  alloc((size_t)NN * 4);
  int*   eids  = (int*)  alloc((size_t)EE * 4);
  int*   eidp  = (int*)  alloc((size_t)MPE * 4);
  int*   srcp  = (int*)  alloc((size_t)EE * 4);
  u16*   accv  = (u16*)  alloc((size_t)MPN * 256 * 2);
  u16*   aggef = (u16*)  alloc((size_t)MPN * 256 * 2);
  if(off > ws_size) return;   // workspace too small -> visible validation failure

  // prep (conversions + weights) with dst-count fused; then CSR chain
  hipMemsetAsync(cnt, 0, (size_t)NN * 4, stream);
  prep_all_k<<<PG6, 256, 0, stream>>>(x, eattr, P, Wne, Wee, dst, cnt,
      xbf, eabf, Wcat, Wet, WqBF, WeBF, biasc, Wnet, Weet);
  scan_k  <<<1, 1024, 0, stream>>>(cnt, offs, cursor);
  scatter_k<<<(EE + 255) / 256, 256, 0, stream>>>(dst, cursor, eids);
  rank_k  <<<(MPE + 255) / 256, 256, 0, stream>>>(dst, src, offs, eids, eidp, srcp);

  // node encoder + edge encoder + qWe weight GEMMs in one launch
  enc_all_k<<<2672, 256, 0, stream>>>(
      xbf, Wnet, bne, hbf,
      eabf, Weet, bee, efp, eidp,
      WeBF, WqBF, Wcat + (size_t)512 * 256);

  for(int l = 0; l < 3; ++l){
    // fused q|skip|qWe|k|v slab -> qq bf16 + skipf fp16 + kv bf16
    slab_k<<<dim3(MPN / 128, 10), 256, 0, stream>>>(
        hbf, Wcat + (size_t)l * 1280 * 256, biasc + (size_t)l * 1280, qq, kvbf, skipf);
    // per-node attention: scores + exp + weighted sums (pre-divided by denom)
    node_pass_k<<<NN / 4, 256, 0, stream>>>(qq, efp, kvbf, srcp, offs, accv, aggef);
    // out = accv + aggef@We + skip  (+relu, bf16 for layers 0,1; fp32 out for layer 2)
    if(l < 2)
      out3_k<<<dim3(MPN / 128, 2), 256, 0, stream>>>(
          aggef, Wet + (size_t)l * 256 * 256, hbf, accv, skipf);
    else
      out4_k<<<dim3(MPN / 128, 2), 256, 0, stream>>>(
          aggef, Wet + (size_t)l * 256 * 256, (float*)d_out, accv, skipf);
  }
}

// Round 13
// 318.496 us; speedup vs baseline: 1.3000x; 1.0600x over previous
//
#include <hip/hip_runtime.h>
#include <cstdint>

typedef unsigned short u16;
typedef unsigned char u8;
typedef __attribute__((ext_vector_type(8))) short short8;
typedef __attribute__((ext_vector_type(8))) __bf16 bf16x8;
typedef __attribute__((ext_vector_type(4))) float f32x4;
typedef __attribute__((ext_vector_type(2))) float f32x2;

#define DEV __device__ __forceinline__

DEV u16 f2bf(float f){
  uint32_t u = __float_as_uint(f);
  u += 0x7fffu + ((u >> 16) & 1u);
  return (u16)(u >> 16);
}
DEV float bf2f(u16 h){ return __uint_as_float(((uint32_t)h) << 16); }
DEV u16 f2h(float f){ return __builtin_bit_cast(u16, (_Float16)f); }
DEV float h2f(u16 h){ return (float)__builtin_bit_cast(_Float16, h); }

DEV u8 f2fp8(float v){
  return (u8)(__builtin_amdgcn_cvt_pk_fp8_f32(v, v, 0, false) & 0xff);
}
DEV void fp8cvt16(int4 w, float* f){
  f32x2 p;
  p = __builtin_amdgcn_cvt_pk_f32_fp8(w.x, false); f[0]=p[0];  f[1]=p[1];
  p = __builtin_amdgcn_cvt_pk_f32_fp8(w.x, true ); f[2]=p[0];  f[3]=p[1];
  p = __builtin_amdgcn_cvt_pk_f32_fp8(w.y, false); f[4]=p[0];  f[5]=p[1];
  p = __builtin_amdgcn_cvt_pk_f32_fp8(w.y, true ); f[6]=p[0];  f[7]=p[1];
  p = __builtin_amdgcn_cvt_pk_f32_fp8(w.z, false); f[8]=p[0];  f[9]=p[1];
  p = __builtin_amdgcn_cvt_pk_f32_fp8(w.z, true ); f[10]=p[0]; f[11]=p[1];
  p = __builtin_amdgcn_cvt_pk_f32_fp8(w.w, false); f[12]=p[0]; f[13]=p[1];
  p = __builtin_amdgcn_cvt_pk_f32_fp8(w.w, true ); f[14]=p[0]; f[15]=p[1];
}

DEV f32x4 mfma16(short8 a, short8 b, f32x4 c){
  return __builtin_amdgcn_mfma_f32_16x16x32_bf16(
      __builtin_bit_cast(bf16x8, a), __builtin_bit_cast(bf16x8, b), c, 0, 0, 0);
}

#define NN 10000
#define EE 160000
#define MPN 10112   /* 79*128  */
#define MPE 160128  /* 1251*128 */

// ---------------- CSR scan (count fused into prep_all) ----------------
__global__ __launch_bounds__(1024) void scan_k(const int* __restrict__ cnt,
                                               int* __restrict__ offs,
                                               int* __restrict__ cursor){
  __shared__ int psum[1024];
  int tid = threadIdx.x;
  int base = tid * 10;
  int loc[10];
  int s = 0;
  #pragma unroll
  for(int j = 0; j < 10; ++j){
    int idx = base + j;
    int v = (idx < NN) ? cnt[idx] : 0;
    loc[j] = s; s += v;
  }
  psum[tid] = s;
  __syncthreads();
  for(int d = 1; d < 1024; d <<= 1){
    int t = (tid >= d) ? psum[tid - d] : 0;
    __syncthreads();
    psum[tid] += t;
    __syncthreads();
  }
  int add = (tid > 0) ? psum[tid - 1] : 0;
  #pragma unroll
  for(int j = 0; j < 10; ++j){
    int idx = base + j;
    if(idx < NN){ int v = loc[j] + add; offs[idx] = v; cursor[idx] = v; }
  }
  if(tid == 0) offs[NN] = EE;
}

__global__ void scatter_k(const int* __restrict__ dst, int* __restrict__ cursor,
                          int* __restrict__ eids){
  int i = blockIdx.x * 256 + threadIdx.x;
  if(i < EE){ int p = atomicAdd(&cursor[dst[i]], 1); eids[p] = i; }
}

// deterministic rank: slot(e) = offs[dst] + #{e' in bucket : e' < e}
__global__ void rank_k(const int* __restrict__ dst, const int* __restrict__ src,
                       const int* __restrict__ offs, const int* __restrict__ eids,
                       int* __restrict__ eidp, int* __restrict__ srcp){
  int e = blockIdx.x * 256 + threadIdx.x;
  if(e >= MPE) return;
  if(e >= EE){ eidp[e] = e; return; }      // pad slots -> zero rows of eabf
  int n = dst[e];
  int p0 = offs[n], p1 = offs[n + 1];
  int rk = 0;
  for(int p = p0; p < p1; ++p) rk += (eids[p] < e) ? 1 : 0;
  int slot = p0 + rk;
  eidp[slot] = e;
  srcp[slot] = src[e];
}

// ---------------- weight / input prep + dst-count (single fused kernel) ----------------
struct WPack {
  const float* Wq[3]; const float* Wk[3]; const float* Wv[3];
  const float* Ws[3]; const float* We[3];
  const float* bq[3]; const float* bk[3]; const float* bv[3]; const float* bs[3];
};

#define PG0 5056                 /* xbf   : MPN*128/256 */
#define PG1 (PG0 + 20016)        /* eabf  : MPE*32/256  */
#define PG2 (PG1 + 3840)         /* Wcat/Wet : 3*1280   */
#define PG3 (PG2 + 1536)         /* WqBF/WeBF: 3*512    */
#define PG4 (PG3 + 15)           /* biasc */
#define PG5 (PG4 + 256)          /* encoders */
#define PG6 (PG5 + 625)          /* dst count: EE/256 */

// Wcat rows per layer: [0,256) Wq^T | [256,512) Ws^T | [512,768) qWe (GEMM EPI5)
//                      | [768,1024) Wk^T | [1024,1280) Wv^T
__global__ __launch_bounds__(256) void prep_all_k(
    const float* __restrict__ x, const float* __restrict__ eattr, WPack P,
    const float* __restrict__ Wne, const float* __restrict__ Wee,
    const int* __restrict__ dst, int* __restrict__ cnt,
    u16* __restrict__ xbf, u16* __restrict__ eabf,
    u16* __restrict__ Wcat, u16* __restrict__ Wet,
    u16* __restrict__ WqBF, u16* __restrict__ WeBF,
    float* __restrict__ biasc, u16* __restrict__ Wnet, u16* __restrict__ Weet)
{
  int b = blockIdx.x, tid = threadIdx.x;
  if(b < PG0){
    int i = b * 256 + tid;
    xbf[i] = (i < NN * 128) ? f2bf(x[i]) : (u16)0;
  } else if(b < PG1){
    int i = (b - PG0) * 256 + tid;
    eabf[i] = (i < EE * 32) ? f2bf(eattr[i]) : (u16)0;
  } else if(b < PG2){
    int b2 = b - PG1; int l = b2 / 1280, r = b2 % 1280; int k = tid;
    float v;
    if(r < 256)       v = P.Wq[l][k * 256 + r];
    else if(r < 512)  v = P.Ws[l][k * 256 + (r - 256)];
    else if(r < 768){ Wet[((size_t)l * 256 + (r - 512)) * 256 + k] =
                        f2bf(P.We[l][k * 256 + (r - 512)]); return; }
    else if(r < 1024) v = P.Wk[l][k * 256 + (r - 768)];
    else              v = P.Wv[l][k * 256 + (r - 1024)];
    Wcat[((size_t)l * 1280 + r) * 256 + k] = f2bf(v);
  } else if(b < PG3){
    int b3 = b - PG2; int l = b3 >> 9, rr = b3 & 511; int t = tid;
    if(rr < 256) WqBF[((size_t)l * 256 + rr) * 256 + t] = f2bf(P.Wq[l][rr * 256 + t]);
    else         WeBF[((size_t)l * 256 + (rr - 256)) * 256 + t] = f2bf(P.We[l][(rr - 256) * 256 + t]);
  } else if(b < PG4){
    int b4 = b - PG3; int l = b4 / 5, seg = b4 % 5; int t = tid;
    float v;
    if(seg == 0)      v = P.bq[l][t];
    else if(seg == 1) v = P.bs[l][t];
    else if(seg == 2){
      const float* we = P.We[l] + (size_t)t * 256; const float* bq = P.bq[l];
      float s = 0.f;
      for(int c = 0; c < 256; ++c) s += bq[c] * we[c];
      v = s;
    }
    else if(seg == 3) v = P.bk[l][t];
    else              v = P.bv[l][t];
    biasc[(size_t)l * 1280 + seg * 256 + t] = v;
  } else if(b < PG5){
    int n = b - PG4;
    if(tid < 128) Wnet[n * 128 + tid] = f2bf(Wne[(size_t)tid * 256 + n]);
    if(tid < 32)  Weet[n * 32 + tid]  = f2bf(Wee[(size_t)tid * 256 + n]);
  } else {
    int i = (b - PG5) * 256 + tid;
    if(i < EE) atomicAdd(&cnt[dst[i]], 1);
  }
}

// ---------------- MFMA GEMM body:  C[M,N] = A[M,K](bf16) @ Bt[N,K]^T(bf16) ----------------
// AG: gather A rows through rowmap.
// EPI 0: +bias; sec(by/2): 0 q->Out(ld512) | 1 skip->skipOut fp16(ld256)
//        | 2 qWe->Out(+256) | 3 k->kvout | 4 v->kvout(+256)
// EPI 1: +bias, relu -> bf16 (Out, ld Nld)
// EPI 2: +bias, relu -> fp8 e4m3 (Out, ld Nld bytes)
// EPI 3: acc + accv(fp16) + skip(fp16), relu -> bf16
// EPI 4: acc + accv(fp16) + skip(fp16) -> fp32
// EPI 5: plain -> bf16 (weight-prep GEMM; batched over bz)
template<int BK, int EPI, int AG>
DEV void gemm_body(short8* smem8,
    const u16* __restrict__ A, const u16* __restrict__ Bt,
    const float* __restrict__ bias, void* Out,
    const u16* __restrict__ accvH, const u16* __restrict__ skipH,
    const int* __restrict__ rowmap, u16* __restrict__ kvout,
    u16* __restrict__ skipOut,
    int bx, int by, int bz,
    int Mreal, int Nld, int K, size_t sA, size_t sB, size_t sOb)
{
  constexpr int CPR = BK / 8;           // 16B chunks per LDS row
  constexpr int SW  = (BK == 64) ? 7 : 3;
  u16* Al = (u16*)smem8;
  u16* Bl = Al + 128 * BK;
  A  += (size_t)bz * sA;
  Bt += (size_t)bz * sB;
  Out = (void*)((char*)Out + (size_t)bz * sOb);
  int tid = threadIdx.x, lane = tid & 63;
  int rowBase = bx * 128, colBase = by * 128;
  int wave = tid >> 6, wm = wave >> 1, wn = wave & 1;
  int lr = lane & 15, lk = lane >> 4;
  f32x4 acc[4][4] = {};
  int nkt = K / BK;
  for(int kt = 0; kt < nkt; ++kt){
    __syncthreads();
    for(int ci = tid; ci < 128 * CPR; ci += 256){
      int r = ci / CPR, cb = ci % CPR;
      int ar = AG ? rowmap[rowBase + r] : (rowBase + r);
      int d = (r * CPR + (cb ^ (r & SW))) * 8;     // swizzled dest (u16 units)
      *(short8*)&Al[d] = *(const short8*)&A [(size_t)ar * K + kt * BK + cb * 8];
      *(short8*)&Bl[d] = *(const short8*)&Bt[(size_t)(colBase + r) * K + kt * BK + cb * 8];
    }
    __syncthreads();
    #pragma unroll
    for(int kk = 0; kk < BK / 32; ++kk){
      short8 af[4], bfr[4];
      #pragma unroll
      for(int m = 0; m < 4; ++m){
        int r = wm * 64 + m * 16 + lr;
        int byt = r * (BK * 2) + kk * 64 + lk * 16; byt ^= (r & SW) << 4;
        af[m] = *(const short8*)((const char*)Al + byt);
      }
      #pragma unroll
      for(int n = 0; n < 4; ++n){
        int r = wn * 64 + n * 16 + lr;
        int byt = r * (BK * 2) + kk * 64 + lk * 16; byt ^= (r & SW) << 4;
        bfr[n] = *(const short8*)((const char*)Bl + byt);
      }
      #pragma unroll
      for(int m = 0; m < 4; ++m)
        #pragma unroll
        for(int n = 0; n < 4; ++n)
          acc[m][n] = mfma16(af[m], bfr[n], acc[m][n]);
    }
  }

  // ---------- epilogue: LDS-staged, vectorized 16B stores ----------
  __syncthreads();                       // all ds_reads done before LDS reuse
  if constexpr(EPI == 4){
    float* fs = (float*)smem8;           // [64][128] fp32, two passes
    #pragma unroll
    for(int h = 0; h < 2; ++h){
      if(wm == h){
        #pragma unroll
        for(int m = 0; m < 4; ++m)
          #pragma unroll
          for(int n = 0; n < 4; ++n){
            int cc = wn * 64 + n * 16 + lr;
            int c = colBase + cc;
            #pragma unroll
            for(int j = 0; j < 4; ++j){
              int r2 = m * 16 + lk * 4 + j;
              int r = rowBase + h * 64 + r2;
              fs[r2 * 128 + cc] = acc[m][n][j]
                + h2f(accvH[(size_t)r * 256 + c]) + h2f(skipH[(size_t)r * 256 + c]);
            }
          }
      }
      __syncthreads();
      for(int ch = tid; ch < 2048; ch += 256){
        int rr = ch >> 5, cc = (ch & 31) << 2;
        int r = rowBase + h * 64 + rr;
        if(r < Mreal)
          *(float4*)&((float*)Out)[(size_t)r * Nld + colBase + cc] = *(float4*)&fs[rr * 128 + cc];
      }
      __syncthreads();
    }
  } else if constexpr(EPI == 2){
    u8* us = (u8*)smem8;                 // [128][128] fp8
    #pragma unroll
    for(int m = 0; m < 4; ++m)
      #pragma unroll
      for(int n = 0; n < 4; ++n){
        int cc = wn * 64 + n * 16 + lr;
        #pragma unroll
        for(int j = 0; j < 4; ++j){
          int rr = wm * 64 + m * 16 + lk * 4 + j;
          float v = acc[m][n][j] + bias[colBase + cc];
          us[rr * 128 + cc] = f2fp8(fmaxf(v, 0.f));
        }
      }
    __syncthreads();
    for(int ch = tid; ch < 1024; ch += 256){
      int rr = ch >> 3, cc = (ch & 7) << 4;
      int r = rowBase + rr;
      if(r < Mreal)
        *(int4*)&((u8*)Out)[(size_t)r * Nld + colBase + cc] = *(int4*)&us[rr * 128 + cc];
    }
  } else if constexpr(EPI == 0){
    int sec = by >> 1;                   // 0 q | 1 skip | 2 qWe | 3 k | 4 v
    u16* us = (u16*)smem8;               // [128][128] u16 (bf16 or fp16)
    #pragma unroll
    for(int m = 0; m < 4; ++m)
      #pragma unroll
      for(int n = 0; n < 4; ++n){
        int cc = wn * 64 + n * 16 + lr;
        #pragma unroll
        for(int j = 0; j < 4; ++j){
          int rr = wm * 64 + m * 16 + lk * 4 + j;
          float v = acc[m][n][j] + bias[colBase + cc];
          us[rr * 128 + cc] = (sec == 1) ? f2h(v) : f2bf(v);
        }
      }
    __syncthreads();
    u16* dstp; int cofs, ldd;
    if(sec == 0){ dstp = (u16*)Out; cofs = colBase; ldd = 512; }
    else if(sec == 1){ dstp = skipOut; cofs = colBase - 256; ldd = 256; }
    else if(sec == 2){ dstp = (u16*)Out; cofs = colBase - 256; ldd = 512; }
    else { dstp = kvout; cofs = colBase - 768; ldd = 512; }
    for(int ch = tid; ch < 2048; ch += 256){
      int rr = ch >> 4, cc = (ch & 15) << 3;
      int r = rowBase + rr;
      if(r < Mreal)
        *(short8*)&dstp[(size_t)r * ldd + cofs + cc] = *(short8*)&us[rr * 128 + cc];
    }
  } else {
    // bf16 single-pass: EPI 1 (bias+relu), 3 (accv+skip+relu), 5 (plain)
    u16* us = (u16*)smem8;               // [128][128] bf16
    #pragma unroll
    for(int m = 0; m < 4; ++m)
      #pragma unroll
      for(int n = 0; n < 4; ++n){
        int cc = wn * 64 + n * 16 + lr;
        int c = colBase + cc;
        #pragma unroll
        for(int j = 0; j < 4; ++j){
          int rr = wm * 64 + m * 16 + lk * 4 + j;
          float v = acc[m][n][j];
          if constexpr(EPI == 1){ v += bias[c]; v = fmaxf(v, 0.f); }
          else if constexpr(EPI == 3){
            int r = rowBase + rr;
            v += h2f(accvH[(size_t)r * 256 + c]) + h2f(skipH[(size_t)r * 256 + c]);
            v = fmaxf(v, 0.f);
          }
          us[rr * 128 + cc] = f2bf(v);
        }
      }
    __syncthreads();
    for(int ch = tid; ch < 2048; ch += 256){
      int rr = ch >> 4, cc = (ch & 15) << 3;
      int r = rowBase + rr;
      if(r < Mreal)
        *(short8*)&((u16*)Out)[(size_t)r * Nld + colBase + cc] = *(short8*)&us[rr * 128 + cc];
    }
  }
}

// ---------------- GEMM kernel wrappers ----------------
__global__ __launch_bounds__(256) void slab_k(
    const u16* __restrict__ A, const u16* __restrict__ Bt,
    const float* __restrict__ bias, u16* __restrict__ qq,
    u16* __restrict__ kvout, u16* __restrict__ skipOut){
  __shared__ short8 smem[2048];
  gemm_body<64,0,0>(smem, A, Bt, bias, qq, nullptr, nullptr, nullptr, kvout, skipOut,
                    blockIdx.x, blockIdx.y, 0, NN, 512, 256, 0, 0, 0);
}

__global__ __launch_bounds__(256) void out3_k(
    const u16* __restrict__ A, const u16* __restrict__ Bt, u16* __restrict__ Out,
    const u16* __restrict__ accvH, const u16* __restrict__ skipH){
  __shared__ short8 smem[2048];
  gemm_body<64,3,0>(smem, A, Bt, nullptr, Out, accvH, skipH, nullptr, nullptr, nullptr,
                    blockIdx.x, blockIdx.y, 0, NN, 256, 256, 0, 0, 0);
}

__global__ __launch_bounds__(256) void out4_k(
    const u16* __restrict__ A, const u16* __restrict__ Bt, float* __restrict__ Out,
    const u16* __restrict__ accvH, const u16* __restrict__ skipH){
  __shared__ short8 smem[2048];
  gemm_body<64,4,0>(smem, A, Bt, nullptr, Out, accvH, skipH, nullptr, nullptr, nullptr,
                    blockIdx.x, blockIdx.y, 0, NN, 256, 256, 0, 0, 0);
}

// node-enc (158 blocks) + edge-enc fp8 (2502) + weight GEMMs (12) in one launch
__global__ __launch_bounds__(256) void enc_all_k(
    const u16* __restrict__ xbf, const u16* __restrict__ Wnet,
    const float* __restrict__ bne, u16* __restrict__ hbf,
    const u16* __restrict__ eabf, const u16* __restrict__ Weet,
    const float* __restrict__ bee, u8* __restrict__ efp8, const int* __restrict__ eidp,
    const u16* __restrict__ WeBF, const u16* __restrict__ WqBF, u16* __restrict__ WcatQ){
  __shared__ short8 smem[2048];
  int b = blockIdx.x;
  if(b < 158){
    gemm_body<64,1,0>(smem, xbf, Wnet, bne, hbf, nullptr, nullptr, nullptr, nullptr, nullptr,
                      b >> 1, b & 1, 0, NN, 256, 128, 0, 0, 0);
  } else if(b < 2660){
    int bb = b - 158;
    gemm_body<32,2,1>(smem, eabf, Weet, bee, efp8, nullptr, nullptr, eidp, nullptr, nullptr,
                      bb >> 1, bb & 1, 0, EE, 256, 32, 0, 0, 0);
  } else {
    int bb = b - 2660;   // 12 blocks: bx = bb&1, by = (bb>>1)&1, bz = bb>>2
    gemm_body<64,5,0>(smem, WeBF, WqBF, nullptr, WcatQ, nullptr, nullptr, nullptr, nullptr, nullptr,
                      bb & 1, (bb >> 1) & 1, bb >> 2, 256, 256, 256,
                      (size_t)256 * 256, (size_t)256 * 256, (size_t)1280 * 256 * 2);
  }
}

// ---------------- fused per-node attention pass ----------------
// qq row (ld 512 bf16): q[0:256) qWe[256:512)
// kvbf row (ld 512 bf16): k[0:256) v[256:512)
// efp8 row (ld 256 u8): fp8 e4m3 edge features, CSR slot order
// ONE node per WAVE; 4 groups of 16 lanes INTERLEAVED over the edge list
// (R11-proven structure); 2-edge unroll, direct srcp loads; fp8 dequant via
// v_cvt_pk_f32_fp8. accv/agg written fp16/bf16.
__global__ __launch_bounds__(256) void node_pass_k(
    const u16* __restrict__ qq, const u8* __restrict__ efp8,
    const u16* __restrict__ kvbf,
    const int* __restrict__ srcp, const int* __restrict__ offs,
    u16* __restrict__ accvH, u16* __restrict__ aggef)
{
  int wave = threadIdx.x >> 6, lane = threadIdx.x & 63;
  int n = blockIdx.x * 4 + wave;
  if(n >= NN) return;
  int li = lane & 15, eg = lane >> 4;
  const u16* qrow = qq + (size_t)n * 512 + li * 16;
  short8 qh0 = *(const short8*)(qrow),       qh1 = *(const short8*)(qrow + 8);
  short8 eh0 = *(const short8*)(qrow + 256), eh1 = *(const short8*)(qrow + 264);
  float q[16], e[16];
  #pragma unroll
  for(int d = 0; d < 8; ++d){
    q[d] = bf2f((u16)qh0[d]); q[8 + d] = bf2f((u16)qh1[d]);
    e[d] = bf2f((u16)eh0[d]); e[8 + d] = bf2f((u16)eh1[d]);
  }
  float av[16], ag[16];
  #pragma unroll
  for(int d = 0; d < 16; ++d){ av[d] = 0.f; ag[d] = 0.f; }
  float den = 0.f;
  int p0 = offs[n], pe = offs[n + 1];
  int p = p0 + eg;
  for(; p + 4 < pe; p += 8){
    int s1 = srcp[p], s2 = srcp[p + 4];
    const u16* kv1 = kvbf + ((size_t)s1 << 9) + li * 16;
    const u16* kv2 = kvbf + ((size_t)s2 << 9) + li * 16;
    const u8* e1 = efp8 + (((size_t)p) << 8) + li * 16;
    const u8* e2 = efp8 + (((size_t)(p + 4)) << 8) + li * 16;
    short8 kA1 = *(const short8*)(kv1),       kB1 = *(const short8*)(kv1 + 8);
    short8 vA1 = *(const short8*)(kv1 + 256), vB1 = *(const short8*)(kv1 + 264);
    short8 kA2 = *(const short8*)(kv2),       kB2 = *(const short8*)(kv2 + 8);
    short8 vA2 = *(const short8*)(kv2 + 256), vB2 = *(const short8*)(kv2 + 264);
    int4 fw1 = *(const int4*)(e1);
    int4 fw2 = *(const int4*)(e2);
    float f1[16], f2[16];
    fp8cvt16(fw1, f1); fp8cvt16(fw2, f2);
    float sc1 = 0.f, sc2 = 0.f;
    #pragma unroll
    for(int d = 0; d < 8; ++d){
      sc1 += q[d]   * bf2f((u16)kA1[d]) + e[d]   * f1[d];
      sc1 += q[8+d] * bf2f((u16)kB1[d]) + e[8+d] * f1[8+d];
      sc2 += q[d]   * bf2f((u16)kA2[d]) + e[d]   * f2[d];
      sc2 += q[8+d] * bf2f((u16)kB2[d]) + e[8+d] * f2[8+d];
    }
    sc1 += __shfl_xor(sc1, 1); sc2 += __shfl_xor(sc2, 1);
    sc1 += __shfl_xor(sc1, 2); sc2 += __shfl_xor(sc2, 2);
    sc1 += __shfl_xor(sc1, 4); sc2 += __shfl_xor(sc2, 4);
    sc1 += __shfl_xor(sc1, 8); sc2 += __shfl_xor(sc2, 8);
    float w1 = __expf(sc1 * 0.0625f);
    float w2 = __expf(sc2 * 0.0625f);
    den += w1 + w2;
    #pragma unroll
    for(int d = 0; d < 8; ++d){
      av[d]   += w1 * bf2f((u16)vA1[d]) + w2 * bf2f((u16)vA2[d]);
      av[8+d] += w1 * bf2f((u16)vB1[d]) + w2 * bf2f((u16)vB2[d]);
      ag[d]   += w1 * f1[d]   + w2 * f2[d];
      ag[8+d] += w1 * f1[8+d] + w2 * f2[8+d];
    }
  }
  if(p < pe){
    int s = srcp[p];
    const u16* kvp = kvbf + ((size_t)s << 9) + li * 16;
    const u8* ep = efp8 + (((size_t)p) << 8) + li * 16;
    short8 kA = *(const short8*)(kvp),       kB = *(const short8*)(kvp + 8);
    short8 vA = *(const short8*)(kvp + 256), vB = *(const short8*)(kvp + 264);
    int4 fw = *(const int4*)(ep);
    float f[16]; fp8cvt16(fw, f);
    float part = 0.f;
    #pragma unroll
    for(int d = 0; d < 8; ++d){
      part += q[d]   * bf2f((u16)kA[d]) + e[d]   * f[d];
      part += q[8+d] * bf2f((u16)kB[d]) + e[8+d] * f[8+d];
    }
    part += __shfl_xor(part, 1);
    part += __shfl_xor(part, 2);
    part += __shfl_xor(part, 4);
    part += __shfl_xor(part, 8);
    float wgt = __expf(part * 0.0625f);
    den += wgt;
    #pragma unroll
    for(int d = 0; d < 8; ++d){
      av[d]   += wgt * bf2f((u16)vA[d]);
      av[8+d] += wgt * bf2f((u16)vB[d]);
      ag[d]   += wgt * f[d];
      ag[8+d] += wgt * f[8+d];
    }
  }
  // combine the 4 edge-groups (convergent — all 64 lanes active here)
  #pragma unroll
  for(int d = 0; d < 16; ++d){
    av[d] += __shfl_xor(av[d], 16); av[d] += __shfl_xor(av[d], 32);
    ag[d] += __shfl_xor(ag[d], 16); ag[d] += __shfl_xor(ag[d], 32);
  }
  den += __shfl_xor(den, 16); den += __shfl_xor(den, 32);
  float rden = 1.f / fmaxf(den, 1e-16f);          // pre-divide (linear in We)
  if(eg == 0){
    u16* ao = accvH + (size_t)n * 256 + li * 16;
    #pragma unroll
    for(int t = 0; t < 2; ++t){
      short8 o;
      #pragma unroll
      for(int d = 0; d < 8; ++d) o[d] = (short)f2h(av[t*8+d] * rden);
      *(short8*)(ao + t * 8) = o;
    }
  } else if(eg == 1){
    u16* go = aggef + (size_t)n * 256 + li * 16;
    #pragma unroll
    for(int t = 0; t < 2; ++t){
      short8 o;
      #pragma unroll
      for(int d = 0; d < 8; ++d) o[d] = (short)f2bf(ag[t*8+d] * rden);
      *(short8*)(go + t * 8) = o;
    }
  }
}

// ---------------- launch ----------------
extern "C" void kernel_launch(void* const* d_in, const int* in_sizes, int n_in,
                              void* d_out, int out_size, void* d_ws, size_t ws_size,
                              hipStream_t stream){
  const float* x     = (const float*)d_in[0];
  const float* eattr = (const float*)d_in[1];
  const int*   src   = (const int*)d_in[2];
  const int*   dst   = (const int*)d_in[3];
  const float* Wee   = (const float*)d_in[4];
  const float* bee   = (const float*)d_in[5];
  const float* Wne   = (const float*)d_in[6];
  const float* bne   = (const float*)d_in[7];
  WPack P;
  for(int l = 0; l < 3; ++l){
    const int b = 8 + l * 9;
    P.Wq[l] = (const float*)d_in[b + 0]; P.bq[l] = (const float*)d_in[b + 1];
    P.Wk[l] = (const float*)d_in[b + 2]; P.bk[l] = (const float*)d_in[b + 3];
    P.Wv[l] = (const float*)d_in[b + 4]; P.bv[l] = (const float*)d_in[b + 5];
    P.We[l] = (const float*)d_in[b + 6];
    P.Ws[l] = (const float*)d_in[b + 7]; P.bs[l] = (const float*)d_in[b + 8];
  }

  char* w = (char*)d_ws; size_t off = 0;
  auto alloc = [&](size_t bytes)->char*{
    char* p = w + off; off = (off + bytes + 255) & ~(size_t)255; return p;
  };
  u16*   Wcat  = (u16*)  alloc((size_t)3 * 1280 * 256 * 2);
  u16*   Wet   = (u16*)  alloc((size_t)3 * 256 * 256 * 2);
  u16*   WqBF  = (u16*)  alloc((size_t)3 * 256 * 256 * 2);
  u16*   WeBF  = (u16*)  alloc((size_t)3 * 256 * 256 * 2);
  float* biasc = (float*)alloc((size_t)3 * 1280 * 4);
  u16*   Wnet  = (u16*)  alloc((size_t)256 * 128 * 2);
  u16*   Weet  = (u16*)  alloc((size_t)256 * 32 * 2);
  u16*   xbf   = (u16*)  alloc((size_t)MPN * 128 * 2);
  u16*   eabf  = (u16*)  alloc((size_t)MPE * 32 * 2);
  u16*   hbf   = (u16*)  alloc((size_t)MPN * 256 * 2);
  u16*   qq    = (u16*)  alloc((size_t)MPN * 512 * 2);
  u16*   skipf = (u16*)  alloc((size_t)MPN * 256 * 2);
  u16*   kvbf  = (u16*)  alloc((size_t)MPN * 512 * 2);
  u8*    efp8  = (u8*)   alloc((size_t)MPE * 256);
  int*   cnt   = (int*)  alloc((size_t)NN * 4);
  int*   offs  = (int*)  alloc((size_t)(NN + 1) * 4);
  int*   cursor= (int*)  alloc((size_t)NN * 4);
  int*   eids  = (int*)  alloc((size_t)EE * 4);
  int*   eidp  = (int*)  alloc((size_t)MPE * 4);
  int*   srcp  = (int*)  alloc((size_t)EE * 4);
  u16*   accv  = (u16*)  alloc((size_t)MPN * 256 * 2);
  u16*   aggef = (u16*)  alloc((size_t)MPN * 256 * 2);
  if(off > ws_size) return;   // workspace too small -> visible validation failure

  // prep (conversions + weights) with dst-count fused; then CSR chain
  hipMemsetAsync(cnt, 0, (size_t)NN * 4, stream);
  prep_all_k<<<PG6, 256, 0, stream>>>(x, eattr, P, Wne, Wee, dst, cnt,
      xbf, eabf, Wcat, Wet, WqBF, WeBF, biasc, Wnet, Weet);
  scan_k  <<<1, 1024, 0, stream>>>(cnt, offs, cursor);
  scatter_k<<<(EE + 255) / 256, 256, 0, stream>>>(dst, cursor, eids);
  rank_k  <<<(MPE + 255) / 256, 256, 0, stream>>>(dst, src, offs, eids, eidp, srcp);

  // node encoder + edge encoder (fp8) + qWe weight GEMMs in one launch
  enc_all_k<<<2672, 256, 0, stream>>>(
      xbf, Wnet, bne, hbf,
      eabf, Weet, bee, efp8, eidp,
      WeBF, WqBF, Wcat + (size_t)512 * 256);

  for(int l = 0; l < 3; ++l){
    // fused q|skip|qWe|k|v slab -> qq bf16 + skipf fp16 + kv bf16
    slab_k<<<dim3(MPN / 128, 10), 256, 0, stream>>>(
        hbf, Wcat + (size_t)l * 1280 * 256, biasc + (size_t)l * 1280, qq, kvbf, skipf);
    // per-node attention: scores + exp + weighted sums (pre-divided by denom)
    node_pass_k<<<NN / 4, 256, 0, stream>>>(qq, efp8, kvbf, srcp, offs, accv, aggef);
    // out = accv + aggef@We + skip  (+relu, bf16 for layers 0,1; fp32 out for layer 2)
    if(l < 2)
      out3_k<<<dim3(MPN / 128, 2), 256, 0, stream>>>(
          aggef, Wet + (size_t)l * 256 * 256, hbf, accv, skipf);
    else
      out4_k<<<dim3(MPN / 128, 2), 256, 0, stream>>>(
          aggef, Wet + (size_t)l * 256 * 256, (float*)d_out, accv, skipf);
  }
}

// Round 14
// 294.044 us; speedup vs baseline: 1.4081x; 1.0832x over previous
//
#include <hip/hip_runtime.h>
#include <cstdint>

typedef unsigned short u16;
typedef unsigned char u8;
typedef __attribute__((ext_vector_type(8))) short short8;
typedef __attribute__((ext_vector_type(8))) __bf16 bf16x8;
typedef __attribute__((ext_vector_type(4))) float f32x4;
typedef __attribute__((ext_vector_type(2))) float f32x2;

#define DEV __device__ __forceinline__

DEV u16 f2bf(float f){
  uint32_t u = __float_as_uint(f);
  u += 0x7fffu + ((u >> 16) & 1u);
  return (u16)(u >> 16);
}
DEV float bf2f(u16 h){ return __uint_as_float(((uint32_t)h) << 16); }
DEV u16 f2h(float f){ return __builtin_bit_cast(u16, (_Float16)f); }
DEV float h2f(u16 h){ return (float)__builtin_bit_cast(_Float16, h); }

DEV u8 f2fp8(float v){
  return (u8)(__builtin_amdgcn_cvt_pk_fp8_f32(v, v, 0, false) & 0xff);
}
DEV void fp8cvt16(int4 w, float* f){
  f32x2 p;
  p = __builtin_amdgcn_cvt_pk_f32_fp8(w.x, false); f[0]=p[0];  f[1]=p[1];
  p = __builtin_amdgcn_cvt_pk_f32_fp8(w.x, true ); f[2]=p[0];  f[3]=p[1];
  p = __builtin_amdgcn_cvt_pk_f32_fp8(w.y, false); f[4]=p[0];  f[5]=p[1];
  p = __builtin_amdgcn_cvt_pk_f32_fp8(w.y, true ); f[6]=p[0];  f[7]=p[1];
  p = __builtin_amdgcn_cvt_pk_f32_fp8(w.z, false); f[8]=p[0];  f[9]=p[1];
  p = __builtin_amdgcn_cvt_pk_f32_fp8(w.z, true ); f[10]=p[0]; f[11]=p[1];
  p = __builtin_amdgcn_cvt_pk_f32_fp8(w.w, false); f[12]=p[0]; f[13]=p[1];
  p = __builtin_amdgcn_cvt_pk_f32_fp8(w.w, true ); f[14]=p[0]; f[15]=p[1];
}

DEV f32x4 mfma16(short8 a, short8 b, f32x4 c){
  return __builtin_amdgcn_mfma_f32_16x16x32_bf16(
      __builtin_bit_cast(bf16x8, a), __builtin_bit_cast(bf16x8, b), c, 0, 0, 0);
}

#define NN 10000
#define EE 160000
#define MPN 10112   /* 79*128  */
#define MPE 160128  /* 1251*128 */

// ---------------- CSR scan (count fused into prep_all) ----------------
__global__ __launch_bounds__(1024) void scan_k(const int* __restrict__ cnt,
                                               int* __restrict__ offs,
                                               int* __restrict__ cursor){
  __shared__ int psum[1024];
  int tid = threadIdx.x;
  int base = tid * 10;
  int loc[10];
  int s = 0;
  #pragma unroll
  for(int j = 0; j < 10; ++j){
    int idx = base + j;
    int v = (idx < NN) ? cnt[idx] : 0;
    loc[j] = s; s += v;
  }
  psum[tid] = s;
  __syncthreads();
  for(int d = 1; d < 1024; d <<= 1){
    int t = (tid >= d) ? psum[tid - d] : 0;
    __syncthreads();
    psum[tid] += t;
    __syncthreads();
  }
  int add = (tid > 0) ? psum[tid - 1] : 0;
  #pragma unroll
  for(int j = 0; j < 10; ++j){
    int idx = base + j;
    if(idx < NN){ int v = loc[j] + add; offs[idx] = v; cursor[idx] = v; }
  }
  if(tid == 0) offs[NN] = EE;
}

__global__ void scatter_k(const int* __restrict__ dst, int* __restrict__ cursor,
                          int* __restrict__ eids){
  int i = blockIdx.x * 256 + threadIdx.x;
  if(i < EE){ int p = atomicAdd(&cursor[dst[i]], 1); eids[p] = i; }
}

// deterministic rank: slot(e) = offs[dst] + #{e' in bucket : e' < e}
__global__ void rank_k(const int* __restrict__ dst, const int* __restrict__ src,
                       const int* __restrict__ offs, const int* __restrict__ eids,
                       int* __restrict__ eidp, int* __restrict__ srcp){
  int e = blockIdx.x * 256 + threadIdx.x;
  if(e >= MPE) return;
  if(e >= EE){ eidp[e] = e; return; }      // pad slots -> zero rows of eabf
  int n = dst[e];
  int p0 = offs[n], p1 = offs[n + 1];
  int rk = 0;
  for(int p = p0; p < p1; ++p) rk += (eids[p] < e) ? 1 : 0;
  int slot = p0 + rk;
  eidp[slot] = e;
  srcp[slot] = src[e];
}

// ---------------- weight / input prep + dst-count (single fused kernel) ----------------
struct WPack {
  const float* Wq[3]; const float* Wk[3]; const float* Wv[3];
  const float* Ws[3]; const float* We[3];
  const float* bq[3]; const float* bk[3]; const float* bv[3]; const float* bs[3];
};

#define PG0 5056                 /* xbf   : MPN*128/256 */
#define PG1 (PG0 + 20016)        /* eabf  : MPE*32/256  */
#define PG2 (PG1 + 3840)         /* Wcat/Wet : 3*1280   */
#define PG3 (PG2 + 1536)         /* WqBF/WeBF: 3*512    */
#define PG4 (PG3 + 15)           /* biasc */
#define PG5 (PG4 + 256)          /* encoders */
#define PG6 (PG5 + 625)          /* dst count: EE/256 */

// Wcat rows per layer: [0,256) Wq^T | [256,512) Ws^T | [512,768) qWe (GEMM EPI5)
//                      | [768,1024) Wk^T | [1024,1280) Wv^T
__global__ __launch_bounds__(256) void prep_all_k(
    const float* __restrict__ x, const float* __restrict__ eattr, WPack P,
    const float* __restrict__ Wne, const float* __restrict__ Wee,
    const int* __restrict__ dst, int* __restrict__ cnt,
    u16* __restrict__ xbf, u16* __restrict__ eabf,
    u16* __restrict__ Wcat, u16* __restrict__ Wet,
    u16* __restrict__ WqBF, u16* __restrict__ WeBF,
    float* __restrict__ biasc, u16* __restrict__ Wnet, u16* __restrict__ Weet)
{
  int b = blockIdx.x, tid = threadIdx.x;
  if(b < PG0){
    int i = b * 256 + tid;
    xbf[i] = (i < NN * 128) ? f2bf(x[i]) : (u16)0;
  } else if(b < PG1){
    int i = (b - PG0) * 256 + tid;
    eabf[i] = (i < EE * 32) ? f2bf(eattr[i]) : (u16)0;
  } else if(b < PG2){
    int b2 = b - PG1; int l = b2 / 1280, r = b2 % 1280; int k = tid;
    float v;
    if(r < 256)       v = P.Wq[l][k * 256 + r];
    else if(r < 512)  v = P.Ws[l][k * 256 + (r - 256)];
    else if(r < 768){ Wet[((size_t)l * 256 + (r - 512)) * 256 + k] =
                        f2bf(P.We[l][k * 256 + (r - 512)]); return; }
    else if(r < 1024) v = P.Wk[l][k * 256 + (r - 768)];
    else              v = P.Wv[l][k * 256 + (r - 1024)];
    Wcat[((size_t)l * 1280 + r) * 256 + k] = f2bf(v);
  } else if(b < PG3){
    int b3 = b - PG2; int l = b3 >> 9, rr = b3 & 511; int t = tid;
    if(rr < 256) WqBF[((size_t)l * 256 + rr) * 256 + t] = f2bf(P.Wq[l][rr * 256 + t]);
    else         WeBF[((size_t)l * 256 + (rr - 256)) * 256 + t] = f2bf(P.We[l][(rr - 256) * 256 + t]);
  } else if(b < PG4){
    int b4 = b - PG3; int l = b4 / 5, seg = b4 % 5; int t = tid;
    float v;
    if(seg == 0)      v = P.bq[l][t];
    else if(seg == 1) v = P.bs[l][t];
    else if(seg == 2){
      const float* we = P.We[l] + (size_t)t * 256; const float* bq = P.bq[l];
      float s = 0.f;
      for(int c = 0; c < 256; ++c) s += bq[c] * we[c];
      v = s;
    }
    else if(seg == 3) v = P.bk[l][t];
    else              v = P.bv[l][t];
    biasc[(size_t)l * 1280 + seg * 256 + t] = v;
  } else if(b < PG5){
    int n = b - PG4;
    if(tid < 128) Wnet[n * 128 + tid] = f2bf(Wne[(size_t)tid * 256 + n]);
    if(tid < 32)  Weet[n * 32 + tid]  = f2bf(Wee[(size_t)tid * 256 + n]);
  } else {
    int i = (b - PG5) * 256 + tid;
    if(i < EE) atomicAdd(&cnt[dst[i]], 1);
  }
}

// ---------------- MFMA GEMM body:  C[M,N] = A[M,K](bf16) @ Bt[N,K]^T(bf16) ----------------
// AG: gather A rows through rowmap.
// EPI 0: +bias; sec(by/2): 0 q->Out bf16(ld512) | 1 skip->skipOut fp16(ld256)
//        | 2 qWe->Out(+256) | 3/4 k/v -> kv8 fp8 (ld 512 bytes)
// EPI 1: +bias, relu -> bf16 (Out, ld Nld)
// EPI 2: +bias, relu -> fp8 e4m3 (Out, ld Nld bytes)
// EPI 3: acc + accv(fp16) + skip(fp16), relu -> bf16
// EPI 4: acc + accv(fp16) + skip(fp16) -> fp32
// EPI 5: plain -> bf16 (weight-prep GEMM; batched over bz)
template<int BK, int EPI, int AG>
DEV void gemm_body(short8* smem8,
    const u16* __restrict__ A, const u16* __restrict__ Bt,
    const float* __restrict__ bias, void* Out,
    const u16* __restrict__ accvH, const u16* __restrict__ skipH,
    const int* __restrict__ rowmap, u8* __restrict__ kvout,
    u16* __restrict__ skipOut,
    int bx, int by, int bz,
    int Mreal, int Nld, int K, size_t sA, size_t sB, size_t sOb)
{
  constexpr int CPR = BK / 8;           // 16B chunks per LDS row
  constexpr int SW  = (BK == 64) ? 7 : 3;
  u16* Al = (u16*)smem8;
  u16* Bl = Al + 128 * BK;
  A  += (size_t)bz * sA;
  Bt += (size_t)bz * sB;
  Out = (void*)((char*)Out + (size_t)bz * sOb);
  int tid = threadIdx.x, lane = tid & 63;
  int rowBase = bx * 128, colBase = by * 128;
  int wave = tid >> 6, wm = wave >> 1, wn = wave & 1;
  int lr = lane & 15, lk = lane >> 4;
  f32x4 acc[4][4] = {};
  int nkt = K / BK;
  for(int kt = 0; kt < nkt; ++kt){
    __syncthreads();
    for(int ci = tid; ci < 128 * CPR; ci += 256){
      int r = ci / CPR, cb = ci % CPR;
      int ar = AG ? rowmap[rowBase + r] : (rowBase + r);
      int d = (r * CPR + (cb ^ (r & SW))) * 8;     // swizzled dest (u16 units)
      *(short8*)&Al[d] = *(const short8*)&A [(size_t)ar * K + kt * BK + cb * 8];
      *(short8*)&Bl[d] = *(const short8*)&Bt[(size_t)(colBase + r) * K + kt * BK + cb * 8];
    }
    __syncthreads();
    #pragma unroll
    for(int kk = 0; kk < BK / 32; ++kk){
      short8 af[4], bfr[4];
      #pragma unroll
      for(int m = 0; m < 4; ++m){
        int r = wm * 64 + m * 16 + lr;
        int byt = r * (BK * 2) + kk * 64 + lk * 16; byt ^= (r & SW) << 4;
        af[m] = *(const short8*)((const char*)Al + byt);
      }
      #pragma unroll
      for(int n = 0; n < 4; ++n){
        int r = wn * 64 + n * 16 + lr;
        int byt = r * (BK * 2) + kk * 64 + lk * 16; byt ^= (r & SW) << 4;
        bfr[n] = *(const short8*)((const char*)Bl + byt);
      }
      #pragma unroll
      for(int m = 0; m < 4; ++m)
        #pragma unroll
        for(int n = 0; n < 4; ++n)
          acc[m][n] = mfma16(af[m], bfr[n], acc[m][n]);
    }
  }

  // ---------- epilogue: LDS-staged, vectorized 16B stores ----------
  __syncthreads();                       // all ds_reads done before LDS reuse
  if constexpr(EPI == 4){
    float* fs = (float*)smem8;           // [64][128] fp32, two passes
    #pragma unroll
    for(int h = 0; h < 2; ++h){
      if(wm == h){
        #pragma unroll
        for(int m = 0; m < 4; ++m)
          #pragma unroll
          for(int n = 0; n < 4; ++n){
            int cc = wn * 64 + n * 16 + lr;
            int c = colBase + cc;
            #pragma unroll
            for(int j = 0; j < 4; ++j){
              int r2 = m * 16 + lk * 4 + j;
              int r = rowBase + h * 64 + r2;
              fs[r2 * 128 + cc] = acc[m][n][j]
                + h2f(accvH[(size_t)r * 256 + c]) + h2f(skipH[(size_t)r * 256 + c]);
            }
          }
      }
      __syncthreads();
      for(int ch = tid; ch < 2048; ch += 256){
        int rr = ch >> 5, cc = (ch & 31) << 2;
        int r = rowBase + h * 64 + rr;
        if(r < Mreal)
          *(float4*)&((float*)Out)[(size_t)r * Nld + colBase + cc] = *(float4*)&fs[rr * 128 + cc];
      }
      __syncthreads();
    }
  } else if constexpr(EPI == 2){
    u8* us = (u8*)smem8;                 // [128][128] fp8
    #pragma unroll
    for(int m = 0; m < 4; ++m)
      #pragma unroll
      for(int n = 0; n < 4; ++n){
        int cc = wn * 64 + n * 16 + lr;
        #pragma unroll
        for(int j = 0; j < 4; ++j){
          int rr = wm * 64 + m * 16 + lk * 4 + j;
          float v = acc[m][n][j] + bias[colBase + cc];
          us[rr * 128 + cc] = f2fp8(fmaxf(v, 0.f));
        }
      }
    __syncthreads();
    for(int ch = tid; ch < 1024; ch += 256){
      int rr = ch >> 3, cc = (ch & 7) << 4;
      int r = rowBase + rr;
      if(r < Mreal)
        *(int4*)&((u8*)Out)[(size_t)r * Nld + colBase + cc] = *(int4*)&us[rr * 128 + cc];
    }
  } else if constexpr(EPI == 0){
    int sec = by >> 1;                   // 0 q | 1 skip | 2 qWe | 3 k | 4 v
    if(sec >= 3){
      u8* us = (u8*)smem8;               // [128][128] fp8
      #pragma unroll
      for(int m = 0; m < 4; ++m)
        #pragma unroll
        for(int n = 0; n < 4; ++n){
          int cc = wn * 64 + n * 16 + lr;
          #pragma unroll
          for(int j = 0; j < 4; ++j){
            int rr = wm * 64 + m * 16 + lk * 4 + j;
            us[rr * 128 + cc] = f2fp8(acc[m][n][j] + bias[colBase + cc]);
          }
        }
      __syncthreads();
      int cofs = (by - 6) * 128;         // byte offset in kv8 row (ld 512)
      for(int ch = tid; ch < 1024; ch += 256){
        int rr = ch >> 3, cc = (ch & 7) << 4;
        int r = rowBase + rr;
        if(r < Mreal)
          *(int4*)&kvout[(size_t)r * 512 + cofs + cc] = *(int4*)&us[rr * 128 + cc];
      }
    } else {
      u16* us = (u16*)smem8;             // [128][128] u16 (bf16 or fp16)
      #pragma unroll
      for(int m = 0; m < 4; ++m)
        #pragma unroll
        for(int n = 0; n < 4; ++n){
          int cc = wn * 64 + n * 16 + lr;
          #pragma unroll
          for(int j = 0; j < 4; ++j){
            int rr = wm * 64 + m * 16 + lk * 4 + j;
            float v = acc[m][n][j] + bias[colBase + cc];
            us[rr * 128 + cc] = (sec == 1) ? f2h(v) : f2bf(v);
          }
        }
      __syncthreads();
      u16* dstp; int cofs, ldd;
      if(sec == 0){ dstp = (u16*)Out; cofs = colBase; ldd = 512; }
      else if(sec == 1){ dstp = skipOut; cofs = colBase - 256; ldd = 256; }
      else { dstp = (u16*)Out; cofs = colBase - 256; ldd = 512; }
      for(int ch = tid; ch < 2048; ch += 256){
        int rr = ch >> 4, cc = (ch & 15) << 3;
        int r = rowBase + rr;
        if(r < Mreal)
          *(short8*)&dstp[(size_t)r * ldd + cofs + cc] = *(short8*)&us[rr * 128 + cc];
      }
    }
  } else {
    // bf16 single-pass: EPI 1 (bias+relu), 3 (accv+skip+relu), 5 (plain)
    u16* us = (u16*)smem8;               // [128][128] bf16
    #pragma unroll
    for(int m = 0; m < 4; ++m)
      #pragma unroll
      for(int n = 0; n < 4; ++n){
        int cc = wn * 64 + n * 16 + lr;
        int c = colBase + cc;
        #pragma unroll
        for(int j = 0; j < 4; ++j){
          int rr = wm * 64 + m * 16 + lk * 4 + j;
          float v = acc[m][n][j];
          if constexpr(EPI == 1){ v += bias[c]; v = fmaxf(v, 0.f); }
          else if constexpr(EPI == 3){
            int r = rowBase + rr;
            v += h2f(accvH[(size_t)r * 256 + c]) + h2f(skipH[(size_t)r * 256 + c]);
            v = fmaxf(v, 0.f);
          }
          us[rr * 128 + cc] = f2bf(v);
        }
      }
    __syncthreads();
    for(int ch = tid; ch < 2048; ch += 256){
      int rr = ch >> 4, cc = (ch & 15) << 3;
      int r = rowBase + rr;
      if(r < Mreal)
        *(short8*)&((u16*)Out)[(size_t)r * Nld + colBase + cc] = *(short8*)&us[rr * 128 + cc];
    }
  }
}

// ---------------- GEMM kernel wrappers ----------------
__global__ __launch_bounds__(256) void slab_k(
    const u16* __restrict__ A, const u16* __restrict__ Bt,
    const float* __restrict__ bias, u16* __restrict__ qq,
    u8* __restrict__ kvout, u16* __restrict__ skipOut){
  __shared__ short8 smem[2048];
  gemm_body<64,0,0>(smem, A, Bt, bias, qq, nullptr, nullptr, nullptr, kvout, skipOut,
                    blockIdx.x, blockIdx.y, 0, NN, 512, 256, 0, 0, 0);
}

__global__ __launch_bounds__(256) void out3_k(
    const u16* __restrict__ A, const u16* __restrict__ Bt, u16* __restrict__ Out,
    const u16* __restrict__ accvH, const u16* __restrict__ skipH){
  __shared__ short8 smem[2048];
  gemm_body<64,3,0>(smem, A, Bt, nullptr, Out, accvH, skipH, nullptr, nullptr, nullptr,
                    blockIdx.x, blockIdx.y, 0, NN, 256, 256, 0, 0, 0);
}

__global__ __launch_bounds__(256) void out4_k(
    const u16* __restrict__ A, const u16* __restrict__ Bt, float* __restrict__ Out,
    const u16* __restrict__ accvH, const u16* __restrict__ skipH){
  __shared__ short8 smem[2048];
  gemm_body<64,4,0>(smem, A, Bt, nullptr, Out, accvH, skipH, nullptr, nullptr, nullptr,
                    blockIdx.x, blockIdx.y, 0, NN, 256, 256, 0, 0, 0);
}

// node-enc (158 blocks) + edge-enc fp8 (2502) + weight GEMMs (12) in one launch
__global__ __launch_bounds__(256) void enc_all_k(
    const u16* __restrict__ xbf, const u16* __restrict__ Wnet,
    const float* __restrict__ bne, u16* __restrict__ hbf,
    const u16* __restrict__ eabf, const u16* __restrict__ Weet,
    const float* __restrict__ bee, u8* __restrict__ efp8, const int* __restrict__ eidp,
    const u16* __restrict__ WeBF, const u16* __restrict__ WqBF, u16* __restrict__ WcatQ){
  __shared__ short8 smem[2048];
  int b = blockIdx.x;
  if(b < 158){
    gemm_body<64,1,0>(smem, xbf, Wnet, bne, hbf, nullptr, nullptr, nullptr, nullptr, nullptr,
                      b >> 1, b & 1, 0, NN, 256, 128, 0, 0, 0);
  } else if(b < 2660){
    int bb = b - 158;
    gemm_body<32,2,1>(smem, eabf, Weet, bee, efp8, nullptr, nullptr, eidp, nullptr, nullptr,
                      bb >> 1, bb & 1, 0, EE, 256, 32, 0, 0, 0);
  } else {
    int bb = b - 2660;   // 12 blocks: bx = bb&1, by = (bb>>1)&1, bz = bb>>2
    gemm_body<64,5,0>(smem, WeBF, WqBF, nullptr, WcatQ, nullptr, nullptr, nullptr, nullptr, nullptr,
                      bb & 1, (bb >> 1) & 1, bb >> 2, 256, 256, 256,
                      (size_t)256 * 256, (size_t)256 * 256, (size_t)1280 * 256 * 2);
  }
}

// ---------------- fused per-node attention pass ----------------
// qq row (ld 512 bf16): q[0:256) qWe[256:512)
// kv8 row (ld 512 u8): k fp8 [0:256) v fp8 [256:512)
// efp8 row (ld 256 u8): fp8 e4m3 edge features, CSR slot order
// ONE node per WAVE; 4 groups of 16 lanes INTERLEAVED over the edge list
// (R11-proven structure); 2-edge unroll, direct srcp loads; fp8 dequant via
// v_cvt_pk_f32_fp8. accv/agg written fp16/bf16.
__global__ __launch_bounds__(256) void node_pass_k(
    const u16* __restrict__ qq, const u8* __restrict__ efp8,
    const u8* __restrict__ kv8,
    const int* __restrict__ srcp, const int* __restrict__ offs,
    u16* __restrict__ accvH, u16* __restrict__ aggef)
{
  int wave = threadIdx.x >> 6, lane = threadIdx.x & 63;
  int n = blockIdx.x * 4 + wave;
  if(n >= NN) return;
  int li = lane & 15, eg = lane >> 4;
  const u16* qrow = qq + (size_t)n * 512 + li * 16;
  short8 qh0 = *(const short8*)(qrow),       qh1 = *(const short8*)(qrow + 8);
  short8 eh0 = *(const short8*)(qrow + 256), eh1 = *(const short8*)(qrow + 264);
  float q[16], e[16];
  #pragma unroll
  for(int d = 0; d < 8; ++d){
    q[d] = bf2f((u16)qh0[d]); q[8 + d] = bf2f((u16)qh1[d]);
    e[d] = bf2f((u16)eh0[d]); e[8 + d] = bf2f((u16)eh1[d]);
  }
  float av[16], ag[16];
  #pragma unroll
  for(int d = 0; d < 16; ++d){ av[d] = 0.f; ag[d] = 0.f; }
  float den = 0.f;
  int p0 = offs[n], pe = offs[n + 1];
  int p = p0 + eg;
  for(; p + 4 < pe; p += 8){
    int s1 = srcp[p], s2 = srcp[p + 4];
    const u8* kv1 = kv8 + ((size_t)s1 << 9) + li * 16;
    const u8* kv2 = kv8 + ((size_t)s2 << 9) + li * 16;
    const u8* e1 = efp8 + (((size_t)p) << 8) + li * 16;
    const u8* e2 = efp8 + (((size_t)(p + 4)) << 8) + li * 16;
    int4 kw1 = *(const int4*)(kv1);
    int4 vw1 = *(const int4*)(kv1 + 256);
    int4 fw1 = *(const int4*)(e1);
    int4 kw2 = *(const int4*)(kv2);
    int4 vw2 = *(const int4*)(kv2 + 256);
    int4 fw2 = *(const int4*)(e2);
    float fk1[16], ff1[16], fk2[16], ff2[16];
    fp8cvt16(kw1, fk1); fp8cvt16(fw1, ff1);
    fp8cvt16(kw2, fk2); fp8cvt16(fw2, ff2);
    float sc1 = 0.f, sc2 = 0.f;
    #pragma unroll
    for(int d = 0; d < 16; ++d){
      sc1 += q[d] * fk1[d] + e[d] * ff1[d];
      sc2 += q[d] * fk2[d] + e[d] * ff2[d];
    }
    sc1 += __shfl_xor(sc1, 1); sc2 += __shfl_xor(sc2, 1);
    sc1 += __shfl_xor(sc1, 2); sc2 += __shfl_xor(sc2, 2);
    sc1 += __shfl_xor(sc1, 4); sc2 += __shfl_xor(sc2, 4);
    sc1 += __shfl_xor(sc1, 8); sc2 += __shfl_xor(sc2, 8);
    float w1 = __expf(sc1 * 0.0625f);
    float w2 = __expf(sc2 * 0.0625f);
    den += w1 + w2;
    float fv1[16], fv2[16];
    fp8cvt16(vw1, fv1); fp8cvt16(vw2, fv2);
    #pragma unroll
    for(int d = 0; d < 16; ++d){
      av[d] += w1 * fv1[d] + w2 * fv2[d];
      ag[d] += w1 * ff1[d] + w2 * ff2[d];
    }
  }
  if(p < pe){
    int s = srcp[p];
    const u8* kvp = kv8 + ((size_t)s << 9) + li * 16;
    const u8* ep = efp8 + (((size_t)p) << 8) + li * 16;
    int4 kw = *(const int4*)(kvp);
    int4 vw = *(const int4*)(kvp + 256);
    int4 fw = *(const int4*)(ep);
    float fk[16], ff[16];
    fp8cvt16(kw, fk); fp8cvt16(fw, ff);
    float part = 0.f;
    #pragma unroll
    for(int d = 0; d < 16; ++d) part += q[d] * fk[d] + e[d] * ff[d];
    part += __shfl_xor(part, 1);
    part += __shfl_xor(part, 2);
    part += __shfl_xor(part, 4);
    part += __shfl_xor(part, 8);
    float wgt = __expf(part * 0.0625f);
    den += wgt;
    float fv[16];
    fp8cvt16(vw, fv);
    #pragma unroll
    for(int d = 0; d < 16; ++d){
      av[d] += wgt * fv[d];
      ag[d] += wgt * ff[d];
    }
  }
  // combine the 4 edge-groups (convergent — all 64 lanes active here)
  #pragma unroll
  for(int d = 0; d < 16; ++d){
    av[d] += __shfl_xor(av[d], 16); av[d] += __shfl_xor(av[d], 32);
    ag[d] += __shfl_xor(ag[d], 16); ag[d] += __shfl_xor(ag[d], 32);
  }
  den += __shfl_xor(den, 16); den += __shfl_xor(den, 32);
  float rden = 1.f / fmaxf(den, 1e-16f);          // pre-divide (linear in We)
  if(eg == 0){
    u16* ao = accvH + (size_t)n * 256 + li * 16;
    #pragma unroll
    for(int t = 0; t < 2; ++t){
      short8 o;
      #pragma unroll
      for(int d = 0; d < 8; ++d) o[d] = (short)f2h(av[t*8+d] * rden);
      *(short8*)(ao + t * 8) = o;
    }
  } else if(eg == 1){
    u16* go = aggef + (size_t)n * 256 + li * 16;
    #pragma unroll
    for(int t = 0; t < 2; ++t){
      short8 o;
      #pragma unroll
      for(int d = 0; d < 8; ++d) o[d] = (short)f2bf(ag[t*8+d] * rden);
      *(short8*)(go + t * 8) = o;
    }
  }
}

// ---------------- launch ----------------
extern "C" void kernel_launch(void* const* d_in, const int* in_sizes, int n_in,
                              void* d_out, int out_size, void* d_ws, size_t ws_size,
                              hipStream_t stream){
  const float* x     = (const float*)d_in[0];
  const float* eattr = (const float*)d_in[1];
  const int*   src   = (const int*)d_in[2];
  const int*   dst   = (const int*)d_in[3];
  const float* Wee   = (const float*)d_in[4];
  const float* bee   = (const float*)d_in[5];
  const float* Wne   = (const float*)d_in[6];
  const float* bne   = (const float*)d_in[7];
  WPack P;
  for(int l = 0; l < 3; ++l){
    const int b = 8 + l * 9;
    P.Wq[l] = (const float*)d_in[b + 0]; P.bq[l] = (const float*)d_in[b + 1];
    P.Wk[l] = (const float*)d_in[b + 2]; P.bk[l] = (const float*)d_in[b + 3];
    P.Wv[l] = (const float*)d_in[b + 4]; P.bv[l] = (const float*)d_in[b + 5];
    P.We[l] = (const float*)d_in[b + 6];
    P.Ws[l] = (const float*)d_in[b + 7]; P.bs[l] = (const float*)d_in[b + 8];
  }

  char* w = (char*)d_ws; size_t off = 0;
  auto alloc = [&](size_t bytes)->char*{
    char* p = w + off; off = (off + bytes + 255) & ~(size_t)255; return p;
  };
  u16*   Wcat  = (u16*)  alloc((size_t)3 * 1280 * 256 * 2);
  u16*   Wet   = (u16*)  alloc((size_t)3 * 256 * 256 * 2);
  u16*   WqBF  = (u16*)  alloc((size_t)3 * 256 * 256 * 2);
  u16*   WeBF  = (u16*)  alloc((size_t)3 * 256 * 256 * 2);
  float* biasc = (float*)alloc((size_t)3 * 1280 * 4);
  u16*   Wnet  = (u16*)  alloc((size_t)256 * 128 * 2);
  u16*   Weet  = (u16*)  alloc((size_t)256 * 32 * 2);
  u16*   xbf   = (u16*)  alloc((size_t)MPN * 128 * 2);
  u16*   eabf  = (u16*)  alloc((size_t)MPE * 32 * 2);
  u16*   hbf   = (u16*)  alloc((size_t)MPN * 256 * 2);
  u16*   qq    = (u16*)  alloc((size_t)MPN * 512 * 2);
  u16*   skipf = (u16*)  alloc((size_t)MPN * 256 * 2);
  u8*    kv8   = (u8*)   alloc((size_t)MPN * 512);
  u8*    efp8  = (u8*)   alloc((size_t)MPE * 256);
  int*   cnt   = (int*)  alloc((size_t)NN * 4);
  int*   offs  = (int*)  alloc((size_t)(NN + 1) * 4);
  int*   cursor= (int*)  alloc((size_t)NN * 4);
  int*   eids  = (int*)  alloc((size_t)EE * 4);
  int*   eidp  = (int*)  alloc((size_t)MPE * 4);
  int*   srcp  = (int*)  alloc((size_t)EE * 4);
  u16*   accv  = (u16*)  alloc((size_t)MPN * 256 * 2);
  u16*   aggef = (u16*)  alloc((size_t)MPN * 256 * 2);
  if(off > ws_size) return;   // workspace too small -> visible validation failure

  // prep (conversions + weights) with dst-count fused; then CSR chain
  hipMemsetAsync(cnt, 0, (size_t)NN * 4, stream);
  prep_all_k<<<PG6, 256, 0, stream>>>(x, eattr, P, Wne, Wee, dst, cnt,
      xbf, eabf, Wcat, Wet, WqBF, WeBF, biasc, Wnet, Weet);
  scan_k  <<<1, 1024, 0, stream>>>(cnt, offs, cursor);
  scatter_k<<<(EE + 255) / 256, 256, 0, stream>>>(dst, cursor, eids);
  rank_k  <<<(MPE + 255) / 256, 256, 0, stream>>>(dst, src, offs, eids, eidp, srcp);

  // node encoder + edge encoder (fp8) + qWe weight GEMMs in one launch
  enc_all_k<<<2672, 256, 0, stream>>>(
      xbf, Wnet, bne, hbf,
      eabf, Weet, bee, efp8, eidp,
      WeBF, WqBF, Wcat + (size_t)512 * 256);

  for(int l = 0; l < 3; ++l){
    // fused q|skip|qWe (bf16/fp16) + k|v (fp8) slab
    slab_k<<<dim3(MPN / 128, 10), 256, 0, stream>>>(
        hbf, Wcat + (size_t)l * 1280 * 256, biasc + (size_t)l * 1280, qq, kv8, skipf);
    // per-node attention: scores + exp + weighted sums (pre-divided by denom)
    node_pass_k<<<NN / 4, 256, 0, stream>>>(qq, efp8, kv8, srcp, offs, accv, aggef);
    // out = accv + aggef@We + skip  (+relu, bf16 for layers 0,1; fp32 out for layer 2)
    if(l < 2)
      out3_k<<<dim3(MPN / 128, 2), 256, 0, stream>>>(
          aggef, Wet + (size_t)l * 256 * 256, hbf, accv, skipf);
    else
      out4_k<<<dim3(MPN / 128, 2), 256, 0, stream>>>(
          aggef, Wet + (size_t)l * 256 * 256, (float*)d_out, accv, skipf);
  }
}